// Round 1
// baseline (2753.422 us; speedup 1.0000x reference)
//
#include <hip/hip_runtime.h>
#include <math.h>

// Problem constants (B,S,H fixed by setup_inputs)
constexpr int Bc = 4, Sc = 2048, Hc = 1024, NHc = 16, DKc = 64;

// Workspace layout (in floats). Total ~102 MB.
constexpr size_t QKV  = (size_t)Bc * NHc * Sc * DKc;   // 8,388,608
constexpr size_t ROWS = (size_t)Bc * NHc * Sc;         // 131,072
constexpr size_t QOFF  = 0;
constexpr size_t KOFF  = QKV;
constexpr size_t VOFF  = 2 * QKV;
constexpr size_t MOFF  = 3 * QKV;
constexpr size_t LIOFF = MOFF + ROWS;
constexpr size_t WOFF  = LIOFF + ROWS;
constexpr size_t COFF  = WOFF + ROWS;                  // B*H ctx-sum

#define NEG_INF (-INFINITY)

// ---------------------------------------------------------------------------
// Kernel 1: QKV projections. y[m,n] = sum_k x[m,k] * W[n,k] (+ bv for V).
// Writes into (b, h, s, d) layout. Rows s >= L[b] skipped entirely.
// Q is pre-scaled by 1/sqrt(dk) = 0.125 (exact power of 2).
// ---------------------------------------------------------------------------
__global__ __launch_bounds__(256) void proj_kernel(
    const float* __restrict__ x, const float* __restrict__ Wq,
    const float* __restrict__ Wk, const float* __restrict__ Wv,
    const float* __restrict__ bv, const int* __restrict__ L,
    float* __restrict__ ws)
{
    const int which = blockIdx.z;           // 0=q, 1=k, 2=v
    const int m0 = blockIdx.y * 64;         // row in B*S (tile never crosses b)
    const int n0 = blockIdx.x * 64;
    const int b  = m0 / Sc;
    const int s0 = m0 % Sc;
    const int Lb = L[b];
    if (s0 >= Lb) return;

    const float* __restrict__ W =
        (which == 0) ? Wq : (which == 1) ? Wk : Wv;
    float* __restrict__ out =
        ws + ((which == 0) ? QOFF : (which == 1) ? KOFF : VOFF);

    __shared__ float as[64][17];
    __shared__ float bs[64][17];

    const int tid = threadIdx.x;
    const int tx = tid & 15, ty = tid >> 4;
    const int lr = tid >> 2, lk = (tid & 3) * 4;

    float acc[4][4] = {};

    for (int k0 = 0; k0 < Hc; k0 += 16) {
        float4 av = *(const float4*)(x + (size_t)(m0 + lr) * Hc + k0 + lk);
        float4 wv = *(const float4*)(W + (size_t)(n0 + lr) * Hc + k0 + lk);
        as[lr][lk+0] = av.x; as[lr][lk+1] = av.y; as[lr][lk+2] = av.z; as[lr][lk+3] = av.w;
        bs[lr][lk+0] = wv.x; bs[lr][lk+1] = wv.y; bs[lr][lk+2] = wv.z; bs[lr][lk+3] = wv.w;
        __syncthreads();
        #pragma unroll
        for (int kk = 0; kk < 16; ++kk) {
            float a[4], w[4];
            #pragma unroll
            for (int i = 0; i < 4; ++i) a[i] = as[ty*4+i][kk];
            #pragma unroll
            for (int j = 0; j < 4; ++j) w[j] = bs[tx*4+j][kk];
            #pragma unroll
            for (int i = 0; i < 4; ++i)
                #pragma unroll
                for (int j = 0; j < 4; ++j)
                    acc[i][j] += a[i] * w[j];
        }
        __syncthreads();
    }

    const float qscale = (which == 0) ? 0.125f : 1.0f;
    #pragma unroll
    for (int i = 0; i < 4; ++i) {
        const int s = s0 + ty*4 + i;
        if (s >= Lb) continue;
        #pragma unroll
        for (int j = 0; j < 4; ++j) {
            const int n = n0 + tx*4 + j;
            float val = acc[i][j];
            if (which == 2) val += bv[n];
            val *= qscale;
            const int h = n >> 6, d = n & 63;
            out[(((size_t)b * NHc + h) * Sc + s) * DKc + d] = val;
        }
    }
}

// ---------------------------------------------------------------------------
// Kernel 2: per-query softmax stats (row max m, 1/rowsum linv).
// Block = (b*h, q-tile of 32 rows); 4 waves x 8 rows; lane = key column.
// ---------------------------------------------------------------------------
__global__ __launch_bounds__(256) void rowstats_kernel(
    const int* __restrict__ L, float* __restrict__ ws)
{
    const int bh = blockIdx.x;
    const int b  = bh >> 4;
    const int Lb = L[b];
    const int q0 = blockIdx.y * 32;
    if (q0 >= Lb) return;

    const float* __restrict__ qarr = ws + QOFF + (size_t)bh * Sc * DKc;
    const float* __restrict__ karr = ws + KOFF + (size_t)bh * Sc * DKc;
    float* __restrict__ marr  = ws + MOFF  + (size_t)bh * Sc;
    float* __restrict__ liarr = ws + LIOFF + (size_t)bh * Sc;

    __shared__ float qs[32][68];
    __shared__ float ks[64][68];

    const int tid  = threadIdx.x;
    const int lane = tid & 63;
    const int wave = tid >> 6;

    #pragma unroll
    for (int it = 0; it < 2; ++it) {
        const int idx = tid + it * 256;
        const int r = idx >> 4, dq = (idx & 15) * 4;
        float4 v = *(const float4*)(qarr + (size_t)(q0 + r) * DKc + dq);
        qs[r][dq+0] = v.x; qs[r][dq+1] = v.y; qs[r][dq+2] = v.z; qs[r][dq+3] = v.w;
    }

    float m_r[8], l_r[8];
    #pragma unroll
    for (int rr = 0; rr < 8; ++rr) { m_r[rr] = NEG_INF; l_r[rr] = 0.f; }

    for (int k0 = 0; k0 < Lb; k0 += 64) {
        __syncthreads();
        #pragma unroll
        for (int it = 0; it < 4; ++it) {
            const int idx = tid + it * 256;
            const int r = idx >> 4, dq = (idx & 15) * 4;
            float4 v = *(const float4*)(karr + (size_t)(k0 + r) * DKc + dq);
            ks[r][dq+0] = v.x; ks[r][dq+1] = v.y; ks[r][dq+2] = v.z; ks[r][dq+3] = v.w;
        }
        __syncthreads();

        float sc[8] = {0,0,0,0,0,0,0,0};
        #pragma unroll
        for (int dq = 0; dq < 16; ++dq) {
            float4 kv = *(const float4*)&ks[lane][dq*4];
            #pragma unroll
            for (int rr = 0; rr < 8; ++rr) {
                float4 qv = *(const float4*)&qs[wave*8+rr][dq*4];
                sc[rr] += qv.x*kv.x + qv.y*kv.y + qv.z*kv.z + qv.w*kv.w;
            }
        }

        const bool kval = (k0 + lane) < Lb;
        #pragma unroll
        for (int rr = 0; rr < 8; ++rr) {
            float s = kval ? sc[rr] : NEG_INF;
            float tm = s;
            #pragma unroll
            for (int off = 32; off > 0; off >>= 1)
                tm = fmaxf(tm, __shfl_xor(tm, off, 64));
            const float nm = fmaxf(m_r[rr], tm);
            float ps = __expf(s - nm);
            #pragma unroll
            for (int off = 32; off > 0; off >>= 1)
                ps += __shfl_xor(ps, off, 64);
            l_r[rr] = l_r[rr] * __expf(m_r[rr] - nm) + ps;
            m_r[rr] = nm;
        }
    }

    #pragma unroll
    for (int rr = 0; rr < 8; ++rr) {
        if (lane == rr) {
            const int qrow = q0 + wave * 8 + rr;
            if (qrow < Lb) {
                marr[qrow]  = m_r[rr];
                liarr[qrow] = 1.0f / l_r[rr];
            }
        }
    }
}

// ---------------------------------------------------------------------------
// Kernel 3: attention column sums w[k] = sum_{q<L} attn[q,k].
// Block = (b*h, k-tile of 64); block owns its keys -> no atomics.
// ---------------------------------------------------------------------------
__global__ __launch_bounds__(256) void colsum_kernel(
    const int* __restrict__ L, float* __restrict__ ws)
{
    const int bh = blockIdx.x;
    const int b  = bh >> 4;
    const int Lb = L[b];
    const int k0 = blockIdx.y * 64;
    if (k0 >= Lb) return;

    const float* __restrict__ qarr  = ws + QOFF + (size_t)bh * Sc * DKc;
    const float* __restrict__ karr  = ws + KOFF + (size_t)bh * Sc * DKc;
    const float* __restrict__ marr  = ws + MOFF  + (size_t)bh * Sc;
    const float* __restrict__ liarr = ws + LIOFF + (size_t)bh * Sc;
    float* __restrict__ warr = ws + WOFF + (size_t)bh * Sc;

    __shared__ float ks[64][68];
    __shared__ float qs[32][68];
    __shared__ float wred[4][64];

    const int tid  = threadIdx.x;
    const int lane = tid & 63;
    const int wave = tid >> 6;

    #pragma unroll
    for (int it = 0; it < 4; ++it) {
        const int idx = tid + it * 256;
        const int r = idx >> 4, dq = (idx & 15) * 4;
        float4 v = *(const float4*)(karr + (size_t)(k0 + r) * DKc + dq);
        ks[r][dq+0] = v.x; ks[r][dq+1] = v.y; ks[r][dq+2] = v.z; ks[r][dq+3] = v.w;
    }

    float wacc = 0.f;
    const bool kval = (k0 + lane) < Lb;

    for (int q0 = 0; q0 < Lb; q0 += 32) {
        __syncthreads();
        #pragma unroll
        for (int it = 0; it < 2; ++it) {
            const int idx = tid + it * 256;
            const int r = idx >> 4, dq = (idx & 15) * 4;
            float4 v = *(const float4*)(qarr + (size_t)(q0 + r) * DKc + dq);
            qs[r][dq+0] = v.x; qs[r][dq+1] = v.y; qs[r][dq+2] = v.z; qs[r][dq+3] = v.w;
        }
        __syncthreads();

        float sc[8] = {0,0,0,0,0,0,0,0};
        #pragma unroll
        for (int dq = 0; dq < 16; ++dq) {
            float4 kv = *(const float4*)&ks[lane][dq*4];
            #pragma unroll
            for (int rr = 0; rr < 8; ++rr) {
                float4 qv = *(const float4*)&qs[wave*8+rr][dq*4];
                sc[rr] += qv.x*kv.x + qv.y*kv.y + qv.z*kv.z + qv.w*kv.w;
            }
        }

        #pragma unroll
        for (int rr = 0; rr < 8; ++rr) {
            const int qrow = q0 + wave * 8 + rr;
            if (qrow < Lb) {
                float s = kval ? sc[rr] : NEG_INF;
                wacc += __expf(s - marr[qrow]) * liarr[qrow];
            }
        }
    }

    wred[wave][lane] = wacc;
    __syncthreads();
    if (wave == 0 && kval)
        warr[k0 + lane] = wred[0][lane] + wred[1][lane] + wred[2][lane] + wred[3][lane];
}

// ---------------------------------------------------------------------------
// Kernel 4: ctxsum[b,h,d] = sum_{k<L} w[k] * v[k,d]  -> c[b, h*64+d]
// ---------------------------------------------------------------------------
__global__ __launch_bounds__(256) void ctx_kernel(
    const int* __restrict__ L, float* __restrict__ ws)
{
    const int bh = blockIdx.x;
    const int b  = bh >> 4;
    const int Lb = L[b];
    const float* __restrict__ v = ws + VOFF + (size_t)bh * Sc * DKc;
    const float* __restrict__ w = ws + WOFF + (size_t)bh * Sc;
    float* __restrict__ c = ws + COFF;

    const int tid = threadIdx.x;
    const int d = tid & 63, slice = tid >> 6;
    float acc = 0.f;
    for (int k = slice; k < Lb; k += 4)
        acc += w[k] * v[(size_t)k * DKc + d];
    __shared__ float red[4][64];
    red[slice][d] = acc;
    __syncthreads();
    if (tid < 64)
        c[(size_t)b * Hc + (bh & 15) * 64 + tid] =
            red[0][tid] + red[1][tid] + red[2][tid] + red[3][tid];
}

// ---------------------------------------------------------------------------
// Kernel 5: pooled[b,n] = (c[b,:] @ Wo[n,:]) / L[b] + bo[n]
// ---------------------------------------------------------------------------
__global__ __launch_bounds__(256) void out_kernel(
    const float* __restrict__ Wo, const float* __restrict__ bo,
    const int* __restrict__ L, const float* __restrict__ ws,
    float* __restrict__ out)
{
    const int b = blockIdx.y;
    const int n = blockIdx.x * 256 + threadIdx.x;
    __shared__ float cs[Hc];
    const float* __restrict__ c = ws + COFF + (size_t)b * Hc;
    for (int i = threadIdx.x; i < Hc; i += 256) cs[i] = c[i];
    __syncthreads();
    const float* __restrict__ wrow = Wo + (size_t)n * Hc;
    float acc = 0.f;
    for (int h = 0; h < Hc; h += 4) {
        float4 wv = *(const float4*)(wrow + h);
        acc += wv.x*cs[h] + wv.y*cs[h+1] + wv.z*cs[h+2] + wv.w*cs[h+3];
    }
    out[(size_t)b * Hc + n] = acc / (float)L[b] + bo[n];
}

// ---------------------------------------------------------------------------
extern "C" void kernel_launch(void* const* d_in, const int* in_sizes, int n_in,
                              void* d_out, int out_size, void* d_ws, size_t ws_size,
                              hipStream_t stream)
{
    (void)in_sizes; (void)n_in; (void)out_size; (void)ws_size;
    const float* x  = (const float*)d_in[0];
    const int*   L  = (const int*)d_in[1];
    const float* Wq = (const float*)d_in[2];
    const float* Wk = (const float*)d_in[3];
    const float* Wv = (const float*)d_in[4];
    const float* bv = (const float*)d_in[5];
    const float* Wo = (const float*)d_in[6];
    const float* bo = (const float*)d_in[7];
    float* out = (float*)d_out;
    float* ws  = (float*)d_ws;

    dim3 gp(Hc / 64, (Bc * Sc) / 64, 3);
    proj_kernel<<<gp, 256, 0, stream>>>(x, Wq, Wk, Wv, bv, L, ws);

    dim3 gr(Bc * NHc, Sc / 32);
    rowstats_kernel<<<gr, 256, 0, stream>>>(L, ws);

    dim3 gc(Bc * NHc, Sc / 64);
    colsum_kernel<<<gc, 256, 0, stream>>>(L, ws);

    ctx_kernel<<<Bc * NHc, 256, 0, stream>>>(L, ws);

    dim3 go(Hc / 256, Bc);
    out_kernel<<<go, 256, 0, stream>>>(Wo, bo, L, ws, out);
}

// Round 2
// 981.011 us; speedup vs baseline: 2.8067x; 2.8067x over previous
//
#include <hip/hip_runtime.h>
#include <hip/hip_bf16.h>
#include <math.h>

// Problem constants (B,S,H fixed by setup_inputs)
constexpr int Bc = 4, Sc = 2048, Hc = 1024, NHc = 16, DKc = 64;

// Workspace layout (in float units).
constexpr size_t QKV  = (size_t)Bc * NHc * Sc * DKc;   // 8,388,608 elements
constexpr size_t ROWS = (size_t)Bc * NHc * Sc;         // 131,072
constexpr size_t QOFF  = 0;            // Q bf16: QKV shorts = QKV/2 floats
constexpr size_t KOFF  = QKV / 2;      // K bf16: QKV shorts
constexpr size_t VOFF  = QKV;          // V fp32: QKV floats
constexpr size_t LIOFF = VOFF + QKV;   // 1/rowsum per (bh,q)
constexpr size_t WOFF  = LIOFF + ROWS; // attention column sums per (bh,k)
constexpr size_t COFF  = WOFF + ROWS;  // B*H ctx-sum

typedef __attribute__((ext_vector_type(8))) short bf16x8;  // 8 bf16 (4 VGPRs)
typedef __attribute__((ext_vector_type(4))) float f32x4;

// ---------------------------------------------------------------------------
// Kernel 1: QKV projections. y[m,n] = sum_k x[m,k] * W[n,k] (+ bv for V).
// Q,K written bf16 (Q pre-scaled by 1/sqrt(dk)=0.125); V written fp32.
// (b,h,s,d) layout, d contiguous. Rows s >= L[b] skipped (stay poisoned;
// poison bytes 0xAA decode to ~1e-13 in bf16 -> harmless in masked math).
// ---------------------------------------------------------------------------
__global__ __launch_bounds__(256) void proj_kernel(
    const float* __restrict__ x, const float* __restrict__ Wq,
    const float* __restrict__ Wk, const float* __restrict__ Wv,
    const float* __restrict__ bv, const int* __restrict__ L,
    float* __restrict__ ws)
{
    const int which = blockIdx.z;           // 0=q, 1=k, 2=v
    const int m0 = blockIdx.y * 64;         // row in B*S (tile never crosses b)
    const int n0 = blockIdx.x * 64;
    const int b  = m0 / Sc;
    const int s0 = m0 % Sc;
    const int Lb = L[b];
    if (s0 >= Lb) return;

    const float* __restrict__ W =
        (which == 0) ? Wq : (which == 1) ? Wk : Wv;

    __shared__ float as[64][17];
    __shared__ float bs[64][17];

    const int tid = threadIdx.x;
    const int tx = tid & 15, ty = tid >> 4;
    const int lr = tid >> 2, lk = (tid & 3) * 4;

    float acc[4][4] = {};

    for (int k0 = 0; k0 < Hc; k0 += 16) {
        float4 av = *(const float4*)(x + (size_t)(m0 + lr) * Hc + k0 + lk);
        float4 wv = *(const float4*)(W + (size_t)(n0 + lr) * Hc + k0 + lk);
        as[lr][lk+0] = av.x; as[lr][lk+1] = av.y; as[lr][lk+2] = av.z; as[lr][lk+3] = av.w;
        bs[lr][lk+0] = wv.x; bs[lr][lk+1] = wv.y; bs[lr][lk+2] = wv.z; bs[lr][lk+3] = wv.w;
        __syncthreads();
        #pragma unroll
        for (int kk = 0; kk < 16; ++kk) {
            float a[4], w[4];
            #pragma unroll
            for (int i = 0; i < 4; ++i) a[i] = as[ty*4+i][kk];
            #pragma unroll
            for (int j = 0; j < 4; ++j) w[j] = bs[tx*4+j][kk];
            #pragma unroll
            for (int i = 0; i < 4; ++i)
                #pragma unroll
                for (int j = 0; j < 4; ++j)
                    acc[i][j] += a[i] * w[j];
        }
        __syncthreads();
    }

    #pragma unroll
    for (int i = 0; i < 4; ++i) {
        const int s = s0 + ty*4 + i;
        if (s >= Lb) continue;
        #pragma unroll
        for (int j = 0; j < 4; ++j) {
            const int n = n0 + tx*4 + j;
            const int h = n >> 6, d = n & 63;
            const size_t idx = (((size_t)b * NHc + h) * Sc + s) * DKc + d;
            if (which == 2) {
                (ws + VOFF)[idx] = acc[i][j] + bv[n];
            } else {
                __hip_bfloat16* o = (__hip_bfloat16*)(ws + (which == 0 ? QOFF : KOFF));
                o[idx] = __float2bfloat16(acc[i][j] * (which == 0 ? 0.125f : 1.0f));
            }
        }
    }
}

// ---------------------------------------------------------------------------
// Kernel 2: row sums l_q = sum_{k<L} exp(s_qk), stored as 1/l.
// Fixed softmax shift of 0 (scores bounded ~|10| << 88, exp never overflows).
// MFMA 16x16x32 bf16: A = K-tile (m=key), B = Q-frag (n=query).
// C layout: col=lane&15=q, row=quad*4+reg=key -> one scalar rowsum acc/lane.
// No LDS, no barriers; fragments loaded straight from global (L2-resident).
// ---------------------------------------------------------------------------
__global__ __launch_bounds__(256) void rowsum_kernel(
    const int* __restrict__ L, float* __restrict__ ws)
{
    const int bh = blockIdx.x;
    const int b  = bh >> 4;
    const int Lb = L[b];
    const int wave = threadIdx.x >> 6;
    const int lane = threadIdx.x & 63;
    const int q0 = blockIdx.y * 128 + wave * 32;   // this wave's 32 queries
    if (q0 >= Lb) return;

    const short* __restrict__ qarr = (const short*)(ws + QOFF) + (size_t)bh * Sc * DKc;
    const short* __restrict__ karr = (const short*)(ws + KOFF) + (size_t)bh * Sc * DKc;
    float* __restrict__ liarr = ws + LIOFF + (size_t)bh * Sc;

    const int l16 = lane & 15, quad = lane >> 4;

    const short* qrow0 = qarr + (size_t)(q0 + l16) * DKc;
    const short* qrow1 = qarr + (size_t)(q0 + 16 + l16) * DKc;
    const bf16x8 b0lo = *(const bf16x8*)(qrow0 + quad * 8);
    const bf16x8 b0hi = *(const bf16x8*)(qrow0 + 32 + quad * 8);
    const bf16x8 b1lo = *(const bf16x8*)(qrow1 + quad * 8);
    const bf16x8 b1hi = *(const bf16x8*)(qrow1 + 32 + quad * 8);

    float lacc0 = 0.f, lacc1 = 0.f;
    for (int k0 = 0; k0 < Lb; k0 += 16) {
        const short* krow = karr + (size_t)(k0 + l16) * DKc;
        const bf16x8 alo = *(const bf16x8*)(krow + quad * 8);
        const bf16x8 ahi = *(const bf16x8*)(krow + 32 + quad * 8);
        f32x4 c0 = {0.f, 0.f, 0.f, 0.f}, c1 = {0.f, 0.f, 0.f, 0.f};
        c0 = __builtin_amdgcn_mfma_f32_16x16x32_bf16(alo, b0lo, c0, 0, 0, 0);
        c0 = __builtin_amdgcn_mfma_f32_16x16x32_bf16(ahi, b0hi, c0, 0, 0, 0);
        c1 = __builtin_amdgcn_mfma_f32_16x16x32_bf16(alo, b1lo, c1, 0, 0, 0);
        c1 = __builtin_amdgcn_mfma_f32_16x16x32_bf16(ahi, b1hi, c1, 0, 0, 0);
        #pragma unroll
        for (int r = 0; r < 4; ++r) {
            if (k0 + quad * 4 + r < Lb) {   // mask padded keys
                lacc0 += __expf(c0[r]);
                lacc1 += __expf(c1[r]);
            }
        }
    }
    // sum over the 4 quads (keys) -> full row sum for q = q0(+16) + l16
    lacc0 += __shfl_xor(lacc0, 16, 64); lacc0 += __shfl_xor(lacc0, 32, 64);
    lacc1 += __shfl_xor(lacc1, 16, 64); lacc1 += __shfl_xor(lacc1, 32, 64);
    if (quad == 0 && q0 + l16 < Lb)      liarr[q0 + l16]      = 1.0f / lacc0;
    if (quad == 1 && q0 + 16 + l16 < Lb) liarr[q0 + 16 + l16] = 1.0f / lacc1;
}

// ---------------------------------------------------------------------------
// Kernel 3: attention column sums w[k] = sum_{q<L} exp(s_qk) / l_q.
// Wave owns 32 keys (A-frags fixed), streams Q tiles of 16. No atomics.
// C layout: col=lane&15=q (one linv per lane), row=quad*4+reg=key.
// ---------------------------------------------------------------------------
__global__ __launch_bounds__(256) void colsum_kernel(
    const int* __restrict__ L, float* __restrict__ ws)
{
    const int bh = blockIdx.x;
    const int b  = bh >> 4;
    const int Lb = L[b];
    const int wave = threadIdx.x >> 6;
    const int lane = threadIdx.x & 63;
    const int k0 = blockIdx.y * 128 + wave * 32;   // this wave's 32 keys
    if (k0 >= Lb) return;

    const short* __restrict__ qarr = (const short*)(ws + QOFF) + (size_t)bh * Sc * DKc;
    const short* __restrict__ karr = (const short*)(ws + KOFF) + (size_t)bh * Sc * DKc;
    const float* __restrict__ liarr = ws + LIOFF + (size_t)bh * Sc;
    float* __restrict__ warr = ws + WOFF + (size_t)bh * Sc;

    const int l16 = lane & 15, quad = lane >> 4;

    const short* krow0 = karr + (size_t)(k0 + l16) * DKc;
    const short* krow1 = karr + (size_t)(k0 + 16 + l16) * DKc;
    const bf16x8 a0lo = *(const bf16x8*)(krow0 + quad * 8);
    const bf16x8 a0hi = *(const bf16x8*)(krow0 + 32 + quad * 8);
    const bf16x8 a1lo = *(const bf16x8*)(krow1 + quad * 8);
    const bf16x8 a1hi = *(const bf16x8*)(krow1 + 32 + quad * 8);

    float w0[4] = {0.f, 0.f, 0.f, 0.f};
    float w1[4] = {0.f, 0.f, 0.f, 0.f};

    for (int q0 = 0; q0 < Lb; q0 += 16) {
        const short* qrow = qarr + (size_t)(q0 + l16) * DKc;
        const bf16x8 blo = *(const bf16x8*)(qrow + quad * 8);
        const bf16x8 bhi = *(const bf16x8*)(qrow + 32 + quad * 8);
        float lv = 0.f;
        if (q0 + l16 < Lb) lv = liarr[q0 + l16];   // 0 kills padded queries
        f32x4 c0 = {0.f, 0.f, 0.f, 0.f}, c1 = {0.f, 0.f, 0.f, 0.f};
        c0 = __builtin_amdgcn_mfma_f32_16x16x32_bf16(a0lo, blo, c0, 0, 0, 0);
        c0 = __builtin_amdgcn_mfma_f32_16x16x32_bf16(a0hi, bhi, c0, 0, 0, 0);
        c1 = __builtin_amdgcn_mfma_f32_16x16x32_bf16(a1lo, blo, c1, 0, 0, 0);
        c1 = __builtin_amdgcn_mfma_f32_16x16x32_bf16(a1hi, bhi, c1, 0, 0, 0);
        #pragma unroll
        for (int r = 0; r < 4; ++r) {
            w0[r] += __expf(c0[r]) * lv;
            w1[r] += __expf(c1[r]) * lv;
        }
    }
    // sum over the 16 q-lanes within each quad
    #pragma unroll
    for (int off = 1; off <= 8; off <<= 1) {
        #pragma unroll
        for (int r = 0; r < 4; ++r) {
            w0[r] += __shfl_xor(w0[r], off, 64);
            w1[r] += __shfl_xor(w1[r], off, 64);
        }
    }
    if (l16 == 0) {
        #pragma unroll
        for (int r = 0; r < 4; ++r) {
            const int ka = k0 + quad * 4 + r;
            if (ka < Lb) warr[ka] = w0[r];
            const int kb = k0 + 16 + quad * 4 + r;
            if (kb < Lb) warr[kb] = w1[r];
        }
    }
}

// ---------------------------------------------------------------------------
// Kernel 4: ctxsum[b,h,d] = sum_{k<L} w[k] * v[k,d]  -> c[b, h*64+d]
// ---------------------------------------------------------------------------
__global__ __launch_bounds__(256) void ctx_kernel(
    const int* __restrict__ L, float* __restrict__ ws)
{
    const int bh = blockIdx.x;
    const int b  = bh >> 4;
    const int Lb = L[b];
    const float* __restrict__ v = ws + VOFF + (size_t)bh * Sc * DKc;
    const float* __restrict__ w = ws + WOFF + (size_t)bh * Sc;
    float* __restrict__ c = ws + COFF;

    const int tid = threadIdx.x;
    const int d = tid & 63, slice = tid >> 6;
    float acc = 0.f;
    for (int k = slice; k < Lb; k += 4)
        acc += w[k] * v[(size_t)k * DKc + d];
    __shared__ float red[4][64];
    red[slice][d] = acc;
    __syncthreads();
    if (tid < 64)
        c[(size_t)b * Hc + (bh & 15) * 64 + tid] =
            red[0][tid] + red[1][tid] + red[2][tid] + red[3][tid];
}

// ---------------------------------------------------------------------------
// Kernel 5: pooled[b,n] = (c[b,:] @ Wo[n,:]) / L[b] + bo[n]
// ---------------------------------------------------------------------------
__global__ __launch_bounds__(256) void out_kernel(
    const float* __restrict__ Wo, const float* __restrict__ bo,
    const int* __restrict__ L, const float* __restrict__ ws,
    float* __restrict__ out)
{
    const int b = blockIdx.y;
    const int n = blockIdx.x * 256 + threadIdx.x;
    __shared__ float cs[Hc];
    const float* __restrict__ c = ws + COFF + (size_t)b * Hc;
    for (int i = threadIdx.x; i < Hc; i += 256) cs[i] = c[i];
    __syncthreads();
    const float* __restrict__ wrow = Wo + (size_t)n * Hc;
    float acc = 0.f;
    for (int h = 0; h < Hc; h += 4) {
        float4 wv = *(const float4*)(wrow + h);
        acc += wv.x*cs[h] + wv.y*cs[h+1] + wv.z*cs[h+2] + wv.w*cs[h+3];
    }
    out[(size_t)b * Hc + n] = acc / (float)L[b] + bo[n];
}

// ---------------------------------------------------------------------------
extern "C" void kernel_launch(void* const* d_in, const int* in_sizes, int n_in,
                              void* d_out, int out_size, void* d_ws, size_t ws_size,
                              hipStream_t stream)
{
    (void)in_sizes; (void)n_in; (void)out_size; (void)ws_size;
    const float* x  = (const float*)d_in[0];
    const int*   L  = (const int*)d_in[1];
    const float* Wq = (const float*)d_in[2];
    const float* Wk = (const float*)d_in[3];
    const float* Wv = (const float*)d_in[4];
    const float* bv = (const float*)d_in[5];
    const float* Wo = (const float*)d_in[6];
    const float* bo = (const float*)d_in[7];
    float* out = (float*)d_out;
    float* ws  = (float*)d_ws;

    dim3 gp(Hc / 64, (Bc * Sc) / 64, 3);
    proj_kernel<<<gp, 256, 0, stream>>>(x, Wq, Wk, Wv, bv, L, ws);

    dim3 gr(Bc * NHc, Sc / 128);
    rowsum_kernel<<<gr, 256, 0, stream>>>(L, ws);

    dim3 gc(Bc * NHc, Sc / 128);
    colsum_kernel<<<gc, 256, 0, stream>>>(L, ws);

    ctx_kernel<<<Bc * NHc, 256, 0, stream>>>(L, ws);

    dim3 go(Hc / 256, Bc);
    out_kernel<<<go, 256, 0, stream>>>(Wo, bo, L, ws, out);
}

// Round 3
// 560.596 us; speedup vs baseline: 4.9116x; 1.7499x over previous
//
#include <hip/hip_runtime.h>
#include <hip/hip_bf16.h>
#include <math.h>

// Problem constants (B,S,H fixed by setup_inputs)
constexpr int Bc = 4, Sc = 2048, Hc = 1024, NHc = 16, DKc = 64;

// Workspace layout (float units). Total ~56 MB.
constexpr size_t XHOFF = 0;                 // x bf16: 8,388,608 shorts
constexpr size_t QOFF  = 4194304;           // Q bf16 (bh,s,d)
constexpr size_t KOFF  = 8388608;           // K bf16 (bh,s,d)
constexpr size_t WQOFF = 12582912;          // Wq bf16 (pre-scaled 0.125)
constexpr size_t WKOFF = 13107200;          // Wk bf16
constexpr size_t LIOFF = 13631488;          // 1/rowsum per (bh,q)
constexpr size_t WOFF  = 13762560;          // attn column sums per (bh,k)
constexpr size_t YOFF  = 13893632;          // y[b,h,j] fp32 (4*16*1024)
constexpr size_t CSOFF = 13959168;          // csum[b,n] (4*1024)

typedef __attribute__((ext_vector_type(8))) short bf16x8;  // 8 bf16 (4 VGPRs)
typedef __attribute__((ext_vector_type(4))) float f32x4;

__device__ inline short f2bf(float v) {
    __hip_bfloat16 h = __float2bfloat16(v);
    return *reinterpret_cast<short*>(&h);
}

__device__ inline void gld_lds16(const void* g, void* l) {
    __builtin_amdgcn_global_load_lds(
        (const __attribute__((address_space(1))) unsigned int*)g,
        (__attribute__((address_space(3))) unsigned int*)l, 16, 0, 0);
}

// ---------------------------------------------------------------------------
// Kernel 0: fp32 -> bf16 conversion (8 elems/thread, packed 16B store).
// ---------------------------------------------------------------------------
__global__ __launch_bounds__(256) void cvt_kernel(
    const float* __restrict__ src, short* __restrict__ dst, float scale)
{
    const size_t i = ((size_t)blockIdx.x * 256 + threadIdx.x) * 8;
    float4 a = *(const float4*)(src + i);
    float4 b = *(const float4*)(src + i + 4);
    bf16x8 o;
    o[0] = f2bf(a.x * scale); o[1] = f2bf(a.y * scale);
    o[2] = f2bf(a.z * scale); o[3] = f2bf(a.w * scale);
    o[4] = f2bf(b.x * scale); o[5] = f2bf(b.y * scale);
    o[6] = f2bf(b.z * scale); o[7] = f2bf(b.w * scale);
    *(bf16x8*)(dst + i) = o;
}

// ---------------------------------------------------------------------------
// Kernel 1: Q/K projections, bf16 MFMA, m97-style 128x128 tile.
// z=0: Q (Wq pre-scaled), z=1: K. Out layout (b,h,s,d) bf16.
// M-tiles fully past L[b] skipped; partial tiles written (downstream masks).
// ---------------------------------------------------------------------------
__global__ __launch_bounds__(256) void proj_mfma_kernel(
    const int* __restrict__ L, float* __restrict__ ws)
{
    const int z  = blockIdx.z;
    const int m0 = blockIdx.y * 128;
    const int n0 = blockIdx.x * 128;
    const int b  = m0 >> 11;
    const int s0 = m0 & 2047;
    const int Lb = L[b];
    if (s0 >= Lb) return;

    const short* __restrict__ A = (const short*)(ws + XHOFF);
    const short* __restrict__ W = (const short*)(ws + (z == 0 ? WQOFF : WKOFF));
    short* __restrict__ Out = (short*)(ws + (z == 0 ? QOFF : KOFF));

    __shared__ __align__(16) short As[128 * 32];
    __shared__ __align__(16) short Bs[128 * 32];

    const int tid  = threadIdx.x;
    const int lane = tid & 63;
    const int wave = tid >> 6;
    const int l16  = lane & 15, quad = lane >> 4;
    const int wm = (wave & 1) * 64, wn = (wave >> 1) * 64;

    // staging chunk geometry: chunk c -> row c>>2, short-offset (c&3)*8
    const int c0 = tid, c1 = tid + 256;
    const int r0 = c0 >> 2, g0 = (c0 & 3) * 8;
    const int r1 = c1 >> 2, g1 = (c1 & 3) * 8;
    short* lA0 = As + wave * 512;
    short* lA1 = As + 2048 + wave * 512;
    short* lB0 = Bs + wave * 512;
    short* lB1 = Bs + 2048 + wave * 512;

    const f32x4 z4 = {0.f, 0.f, 0.f, 0.f};
    f32x4 acc[4][4];
    #pragma unroll
    for (int i = 0; i < 4; ++i)
        #pragma unroll
        for (int j = 0; j < 4; ++j) acc[i][j] = z4;

    for (int k0 = 0; k0 < Hc; k0 += 32) {
        __syncthreads();   // previous iteration's ds_reads done
        gld_lds16(A + (size_t)(m0 + r0) * Hc + k0 + g0, lA0);
        gld_lds16(A + (size_t)(m0 + r1) * Hc + k0 + g1, lA1);
        gld_lds16(W + (size_t)(n0 + r0) * Hc + k0 + g0, lB0);
        gld_lds16(W + (size_t)(n0 + r1) * Hc + k0 + g1, lB1);
        __syncthreads();   // vmcnt(0) drain + barrier

        bf16x8 af[4], bfr[4];
        #pragma unroll
        for (int mt = 0; mt < 4; ++mt)
            af[mt] = *(const bf16x8*)(As + (wm + mt * 16 + l16) * 32 + quad * 8);
        #pragma unroll
        for (int nt = 0; nt < 4; ++nt)
            bfr[nt] = *(const bf16x8*)(Bs + (wn + nt * 16 + l16) * 32 + quad * 8);
        #pragma unroll
        for (int mt = 0; mt < 4; ++mt)
            #pragma unroll
            for (int nt = 0; nt < 4; ++nt)
                acc[mt][nt] = __builtin_amdgcn_mfma_f32_16x16x32_bf16(
                    af[mt], bfr[nt], acc[mt][nt], 0, 0, 0);
    }

    // Epilogue: C row = m (quad*4+r), col = n (l16). Write bf16 (b,h,s,d).
    #pragma unroll
    for (int mt = 0; mt < 4; ++mt) {
        #pragma unroll
        for (int nt = 0; nt < 4; ++nt) {
            const int n = n0 + wn + nt * 16 + l16;
            const int h = n >> 6, d = n & 63;
            #pragma unroll
            for (int r = 0; r < 4; ++r) {
                const int s = s0 + wm + mt * 16 + quad * 4 + r;
                Out[(((size_t)b * NHc + h) * Sc + s) * DKc + d] =
                    f2bf(acc[mt][nt][r]);
            }
        }
    }
}

// ---------------------------------------------------------------------------
// Kernel 2: row sums l_q = sum_{k<L} exp(s_qk), stored as 1/l.
// ---------------------------------------------------------------------------
__global__ __launch_bounds__(256) void rowsum_kernel(
    const int* __restrict__ L, float* __restrict__ ws)
{
    const int bh = blockIdx.x;
    const int b  = bh >> 4;
    const int Lb = L[b];
    const int wave = threadIdx.x >> 6;
    const int lane = threadIdx.x & 63;
    const int q0 = blockIdx.y * 128 + wave * 32;
    if (q0 >= Lb) return;

    const short* __restrict__ qarr = (const short*)(ws + QOFF) + (size_t)bh * Sc * DKc;
    const short* __restrict__ karr = (const short*)(ws + KOFF) + (size_t)bh * Sc * DKc;
    float* __restrict__ liarr = ws + LIOFF + (size_t)bh * Sc;

    const int l16 = lane & 15, quad = lane >> 4;

    const short* qrow0 = qarr + (size_t)(q0 + l16) * DKc;
    const short* qrow1 = qarr + (size_t)(q0 + 16 + l16) * DKc;
    const bf16x8 b0lo = *(const bf16x8*)(qrow0 + quad * 8);
    const bf16x8 b0hi = *(const bf16x8*)(qrow0 + 32 + quad * 8);
    const bf16x8 b1lo = *(const bf16x8*)(qrow1 + quad * 8);
    const bf16x8 b1hi = *(const bf16x8*)(qrow1 + 32 + quad * 8);

    float lacc0 = 0.f, lacc1 = 0.f;
    for (int k0 = 0; k0 < Lb; k0 += 16) {
        const short* krow = karr + (size_t)(k0 + l16) * DKc;
        const bf16x8 alo = *(const bf16x8*)(krow + quad * 8);
        const bf16x8 ahi = *(const bf16x8*)(krow + 32 + quad * 8);
        f32x4 c0 = {0.f, 0.f, 0.f, 0.f}, c1 = {0.f, 0.f, 0.f, 0.f};
        c0 = __builtin_amdgcn_mfma_f32_16x16x32_bf16(alo, b0lo, c0, 0, 0, 0);
        c0 = __builtin_amdgcn_mfma_f32_16x16x32_bf16(ahi, b0hi, c0, 0, 0, 0);
        c1 = __builtin_amdgcn_mfma_f32_16x16x32_bf16(alo, b1lo, c1, 0, 0, 0);
        c1 = __builtin_amdgcn_mfma_f32_16x16x32_bf16(ahi, b1hi, c1, 0, 0, 0);
        #pragma unroll
        for (int r = 0; r < 4; ++r) {
            if (k0 + quad * 4 + r < Lb) {
                lacc0 += __expf(c0[r]);
                lacc1 += __expf(c1[r]);
            }
        }
    }
    lacc0 += __shfl_xor(lacc0, 16, 64); lacc0 += __shfl_xor(lacc0, 32, 64);
    lacc1 += __shfl_xor(lacc1, 16, 64); lacc1 += __shfl_xor(lacc1, 32, 64);
    if (quad == 0 && q0 + l16 < Lb)      liarr[q0 + l16]      = 1.0f / lacc0;
    if (quad == 1 && q0 + 16 + l16 < Lb) liarr[q0 + 16 + l16] = 1.0f / lacc1;
}

// ---------------------------------------------------------------------------
// Kernel 3: attention column sums w[k] = sum_{q<L} exp(s_qk) / l_q.
// ---------------------------------------------------------------------------
__global__ __launch_bounds__(256) void colsum_kernel(
    const int* __restrict__ L, float* __restrict__ ws)
{
    const int bh = blockIdx.x;
    const int b  = bh >> 4;
    const int Lb = L[b];
    const int wave = threadIdx.x >> 6;
    const int lane = threadIdx.x & 63;
    const int k0 = blockIdx.y * 128 + wave * 32;
    if (k0 >= Lb) return;

    const short* __restrict__ qarr = (const short*)(ws + QOFF) + (size_t)bh * Sc * DKc;
    const short* __restrict__ karr = (const short*)(ws + KOFF) + (size_t)bh * Sc * DKc;
    const float* __restrict__ liarr = ws + LIOFF + (size_t)bh * Sc;
    float* __restrict__ warr = ws + WOFF + (size_t)bh * Sc;

    const int l16 = lane & 15, quad = lane >> 4;

    const short* krow0 = karr + (size_t)(k0 + l16) * DKc;
    const short* krow1 = karr + (size_t)(k0 + 16 + l16) * DKc;
    const bf16x8 a0lo = *(const bf16x8*)(krow0 + quad * 8);
    const bf16x8 a0hi = *(const bf16x8*)(krow0 + 32 + quad * 8);
    const bf16x8 a1lo = *(const bf16x8*)(krow1 + quad * 8);
    const bf16x8 a1hi = *(const bf16x8*)(krow1 + 32 + quad * 8);

    float w0[4] = {0.f, 0.f, 0.f, 0.f};
    float w1[4] = {0.f, 0.f, 0.f, 0.f};

    for (int q0 = 0; q0 < Lb; q0 += 16) {
        const short* qrow = qarr + (size_t)(q0 + l16) * DKc;
        const bf16x8 blo = *(const bf16x8*)(qrow + quad * 8);
        const bf16x8 bhi = *(const bf16x8*)(qrow + 32 + quad * 8);
        float lv = 0.f;
        if (q0 + l16 < Lb) lv = liarr[q0 + l16];
        f32x4 c0 = {0.f, 0.f, 0.f, 0.f}, c1 = {0.f, 0.f, 0.f, 0.f};
        c0 = __builtin_amdgcn_mfma_f32_16x16x32_bf16(a0lo, blo, c0, 0, 0, 0);
        c0 = __builtin_amdgcn_mfma_f32_16x16x32_bf16(a0hi, bhi, c0, 0, 0, 0);
        c1 = __builtin_amdgcn_mfma_f32_16x16x32_bf16(a1lo, blo, c1, 0, 0, 0);
        c1 = __builtin_amdgcn_mfma_f32_16x16x32_bf16(a1hi, bhi, c1, 0, 0, 0);
        #pragma unroll
        for (int r = 0; r < 4; ++r) {
            w0[r] += __expf(c0[r]) * lv;
            w1[r] += __expf(c1[r]) * lv;
        }
    }
    #pragma unroll
    for (int off = 1; off <= 8; off <<= 1) {
        #pragma unroll
        for (int r = 0; r < 4; ++r) {
            w0[r] += __shfl_xor(w0[r], off, 64);
            w1[r] += __shfl_xor(w1[r], off, 64);
        }
    }
    if (l16 == 0) {
        #pragma unroll
        for (int r = 0; r < 4; ++r) {
            const int ka = k0 + quad * 4 + r;
            if (ka < Lb) warr[ka] = w0[r];
            const int kb = k0 + 16 + quad * 4 + r;
            if (kb < Lb) warr[kb] = w1[r];
        }
    }
}

// ---------------------------------------------------------------------------
// Kernel 4: y[b,h,j] = sum_{s<L} w[b,h,s] * x[b,s,j]  (exact fp32 V path).
// Block = (j-chunk of 64, b); 64 j-lanes x 4 s-slices; w tiled in LDS.
// ---------------------------------------------------------------------------
__global__ __launch_bounds__(256) void yw_kernel(
    const float* __restrict__ x, const int* __restrict__ L,
    float* __restrict__ ws)
{
    const int b  = blockIdx.y;
    const int j0 = blockIdx.x * 64;
    const int Lb = L[b];
    const int js = threadIdx.x & 63;
    const int sl = threadIdx.x >> 6;
    const float* __restrict__ warr = ws + WOFF + (size_t)b * NHc * Sc;
    const float* __restrict__ xb = x + (size_t)b * Sc * Hc;

    __shared__ float wt[128][20];      // [s_local][h], pad 20 for banks+align
    __shared__ float red[4][16][64];

    float acc[16];
    #pragma unroll
    for (int h = 0; h < 16; ++h) acc[h] = 0.f;

    for (int s0 = 0; s0 < Lb; s0 += 128) {
        __syncthreads();
        #pragma unroll
        for (int i = 0; i < 8; ++i) {
            const int s = (threadIdx.x & 15) + 16 * i;
            const int h = threadIdx.x >> 4;
            float v = 0.f;
            if (s0 + s < Lb) v = warr[(size_t)h * Sc + s0 + s];
            wt[s][h] = v;
        }
        __syncthreads();
        const int send = (Lb - s0 < 128) ? (Lb - s0) : 128;
        for (int s = sl; s < send; s += 4) {
            const float xv = xb[(size_t)(s0 + s) * Hc + j0 + js];
            const f32x4 wa = *(const f32x4*)&wt[s][0];
            const f32x4 wb = *(const f32x4*)&wt[s][4];
            const f32x4 wc = *(const f32x4*)&wt[s][8];
            const f32x4 wd = *(const f32x4*)&wt[s][12];
            #pragma unroll
            for (int h = 0; h < 4; ++h) acc[h]      += wa[h] * xv;
            #pragma unroll
            for (int h = 0; h < 4; ++h) acc[4 + h]  += wb[h] * xv;
            #pragma unroll
            for (int h = 0; h < 4; ++h) acc[8 + h]  += wc[h] * xv;
            #pragma unroll
            for (int h = 0; h < 4; ++h) acc[12 + h] += wd[h] * xv;
        }
    }
    __syncthreads();
    #pragma unroll
    for (int h = 0; h < 16; ++h) red[sl][h][js] = acc[h];
    __syncthreads();
    if (sl == 0) {
        #pragma unroll
        for (int h = 0; h < 16; ++h)
            ws[YOFF + ((size_t)b * NHc + h) * Hc + j0 + js] =
                red[0][h][js] + red[1][h][js] + red[2][h][js] + red[3][h][js];
    }
}

// ---------------------------------------------------------------------------
// Kernel 5: csum[b,n] = sum_j y[b,h(n),j]*Wv[n,j] + bv[n]*L[b].
// ---------------------------------------------------------------------------
__global__ __launch_bounds__(256) void csum_kernel(
    const float* __restrict__ Wv, const float* __restrict__ bv,
    const int* __restrict__ L, float* __restrict__ ws)
{
    const int b = blockIdx.y;
    const int n = blockIdx.x * 256 + threadIdx.x;
    const int h0 = (blockIdx.x * 256) >> 6;
    __shared__ float ys[4][1024];
    const float* __restrict__ y = ws + YOFF + ((size_t)b * NHc + h0) * Hc;
    for (int i = threadIdx.x; i < 4096; i += 256) ys[i >> 10][i & 1023] = y[i];
    __syncthreads();
    const int hl = threadIdx.x >> 6;
    const float* __restrict__ wrow = Wv + (size_t)n * Hc;
    float acc = 0.f;
    for (int j = 0; j < Hc; j += 4) {
        float4 wv = *(const float4*)(wrow + j);
        acc += wv.x*ys[hl][j] + wv.y*ys[hl][j+1] + wv.z*ys[hl][j+2] + wv.w*ys[hl][j+3];
    }
    ws[CSOFF + (size_t)b * Hc + n] = acc + bv[n] * (float)L[b];
}

// ---------------------------------------------------------------------------
// Kernel 6: pooled[b,o] = (sum_n csum[b,n]*Wo[o,n]) / L[b] + bo[o].
// ---------------------------------------------------------------------------
__global__ __launch_bounds__(256) void out_kernel(
    const float* __restrict__ Wo, const float* __restrict__ bo,
    const int* __restrict__ L, const float* __restrict__ ws,
    float* __restrict__ out)
{
    const int b = blockIdx.y;
    const int n = blockIdx.x * 256 + threadIdx.x;
    __shared__ float cs[Hc];
    const float* __restrict__ c = ws + CSOFF + (size_t)b * Hc;
    for (int i = threadIdx.x; i < Hc; i += 256) cs[i] = c[i];
    __syncthreads();
    const float* __restrict__ wrow = Wo + (size_t)n * Hc;
    float acc = 0.f;
    for (int h = 0; h < Hc; h += 4) {
        float4 wv = *(const float4*)(wrow + h);
        acc += wv.x*cs[h] + wv.y*cs[h+1] + wv.z*cs[h+2] + wv.w*cs[h+3];
    }
    out[(size_t)b * Hc + n] = acc / (float)L[b] + bo[n];
}

// ---------------------------------------------------------------------------
extern "C" void kernel_launch(void* const* d_in, const int* in_sizes, int n_in,
                              void* d_out, int out_size, void* d_ws, size_t ws_size,
                              hipStream_t stream)
{
    (void)in_sizes; (void)n_in; (void)out_size; (void)ws_size;
    const float* x  = (const float*)d_in[0];
    const int*   L  = (const int*)d_in[1];
    const float* Wq = (const float*)d_in[2];
    const float* Wk = (const float*)d_in[3];
    const float* Wv = (const float*)d_in[4];
    const float* bv = (const float*)d_in[5];
    const float* Wo = (const float*)d_in[6];
    const float* bo = (const float*)d_in[7];
    float* out = (float*)d_out;
    float* ws  = (float*)d_ws;

    // bf16 conversions: x, Wq (x0.125 folded, exact), Wk
    cvt_kernel<<<4096, 256, 0, stream>>>(x,  (short*)(ws + XHOFF), 1.0f);
    cvt_kernel<<<512,  256, 0, stream>>>(Wq, (short*)(ws + WQOFF), 0.125f);
    cvt_kernel<<<512,  256, 0, stream>>>(Wk, (short*)(ws + WKOFF), 1.0f);

    dim3 gp(Hc / 128, (Bc * Sc) / 128, 2);
    proj_mfma_kernel<<<gp, 256, 0, stream>>>(L, ws);

    dim3 gr(Bc * NHc, Sc / 128);
    rowsum_kernel<<<gr, 256, 0, stream>>>(L, ws);
    colsum_kernel<<<gr, 256, 0, stream>>>(L, ws);

    dim3 gy(Hc / 64, Bc);
    yw_kernel<<<gy, 256, 0, stream>>>(x, L, ws);

    dim3 gc(Hc / 256, Bc);
    csum_kernel<<<gc, 256, 0, stream>>>(Wv, bv, L, ws);

    dim3 go(Hc / 256, Bc);
    out_kernel<<<go, 256, 0, stream>>>(Wo, bo, L, ws, out);
}

// Round 4
// 412.634 us; speedup vs baseline: 6.6728x; 1.3586x over previous
//
#include <hip/hip_runtime.h>
#include <hip/hip_bf16.h>
#include <math.h>

// Problem constants (B,S,H fixed by setup_inputs)
constexpr int Bc = 4, Sc = 2048, Hc = 1024, NHc = 16, DKc = 64;

// Workspace layout (float units). Total ~60 MB.
constexpr size_t XHOFF = 0;                 // x bf16: 8,388,608 shorts
constexpr size_t QOFF  = 4194304;           // Q bf16 (bh,s,d)
constexpr size_t KOFF  = 8388608;           // K bf16 (bh,s,d)
constexpr size_t WQOFF = 12582912;          // Wq bf16 (pre-scaled 0.125)
constexpr size_t WKOFF = 13107200;          // Wk bf16
constexpr size_t LIOFF = 13631488;          // 1/rowsum per (bh,q)
constexpr size_t WOFF  = 13762560;          // attn column sums per (bh,k)
constexpr size_t YOFF  = 13893632;          // y[b,h,j] fp32 (4*16*1024)
constexpr size_t CSOFF = 13959168;          // csum[b,n] (4*1024)
constexpr size_t YPOFF = 13963264;          // y partials: 16 chunks x 65536

typedef __attribute__((ext_vector_type(8))) short bf16x8;  // 8 bf16 (4 VGPRs)
typedef __attribute__((ext_vector_type(4))) float f32x4;

__device__ inline short f2bf(float v) {
    __hip_bfloat16 h = __float2bfloat16(v);
    return *reinterpret_cast<short*>(&h);
}

__device__ inline void gld_lds16(const void* g, void* l) {
    __builtin_amdgcn_global_load_lds(
        (const __attribute__((address_space(1))) unsigned int*)g,
        (__attribute__((address_space(3))) unsigned int*)l, 16, 0, 0);
}

// ---------------------------------------------------------------------------
// Kernel 0: fp32 -> bf16 conversion (8 elems/thread, packed 16B store).
// ---------------------------------------------------------------------------
__global__ __launch_bounds__(256) void cvt_kernel(
    const float* __restrict__ src, short* __restrict__ dst, float scale)
{
    const size_t i = ((size_t)blockIdx.x * 256 + threadIdx.x) * 8;
    float4 a = *(const float4*)(src + i);
    float4 b = *(const float4*)(src + i + 4);
    bf16x8 o;
    o[0] = f2bf(a.x * scale); o[1] = f2bf(a.y * scale);
    o[2] = f2bf(a.z * scale); o[3] = f2bf(a.w * scale);
    o[4] = f2bf(b.x * scale); o[5] = f2bf(b.y * scale);
    o[6] = f2bf(b.z * scale); o[7] = f2bf(b.w * scale);
    *(bf16x8*)(dst + i) = o;
}

// ---------------------------------------------------------------------------
// Kernel 1: Q/K projections, bf16 MFMA, m97-style 128x128 tile.
// z=0: Q (Wq pre-scaled), z=1: K. Out layout (b,h,s,d) bf16.
// ---------------------------------------------------------------------------
__global__ __launch_bounds__(256) void proj_mfma_kernel(
    const int* __restrict__ L, float* __restrict__ ws)
{
    const int z  = blockIdx.z;
    const int m0 = blockIdx.y * 128;
    const int n0 = blockIdx.x * 128;
    const int b  = m0 >> 11;
    const int s0 = m0 & 2047;
    const int Lb = L[b];
    if (s0 >= Lb) return;

    const short* __restrict__ A = (const short*)(ws + XHOFF);
    const short* __restrict__ W = (const short*)(ws + (z == 0 ? WQOFF : WKOFF));
    short* __restrict__ Out = (short*)(ws + (z == 0 ? QOFF : KOFF));

    __shared__ __align__(16) short As[128 * 32];
    __shared__ __align__(16) short Bs[128 * 32];

    const int tid  = threadIdx.x;
    const int lane = tid & 63;
    const int wave = tid >> 6;
    const int l16  = lane & 15, quad = lane >> 4;
    const int wm = (wave & 1) * 64, wn = (wave >> 1) * 64;

    const int c0 = tid, c1 = tid + 256;
    const int r0 = c0 >> 2, g0 = (c0 & 3) * 8;
    const int r1 = c1 >> 2, g1 = (c1 & 3) * 8;
    short* lA0 = As + wave * 512;
    short* lA1 = As + 2048 + wave * 512;
    short* lB0 = Bs + wave * 512;
    short* lB1 = Bs + 2048 + wave * 512;

    const f32x4 z4 = {0.f, 0.f, 0.f, 0.f};
    f32x4 acc[4][4];
    #pragma unroll
    for (int i = 0; i < 4; ++i)
        #pragma unroll
        for (int j = 0; j < 4; ++j) acc[i][j] = z4;

    for (int k0 = 0; k0 < Hc; k0 += 32) {
        __syncthreads();
        gld_lds16(A + (size_t)(m0 + r0) * Hc + k0 + g0, lA0);
        gld_lds16(A + (size_t)(m0 + r1) * Hc + k0 + g1, lA1);
        gld_lds16(W + (size_t)(n0 + r0) * Hc + k0 + g0, lB0);
        gld_lds16(W + (size_t)(n0 + r1) * Hc + k0 + g1, lB1);
        __syncthreads();

        bf16x8 af[4], bfr[4];
        #pragma unroll
        for (int mt = 0; mt < 4; ++mt)
            af[mt] = *(const bf16x8*)(As + (wm + mt * 16 + l16) * 32 + quad * 8);
        #pragma unroll
        for (int nt = 0; nt < 4; ++nt)
            bfr[nt] = *(const bf16x8*)(Bs + (wn + nt * 16 + l16) * 32 + quad * 8);
        #pragma unroll
        for (int mt = 0; mt < 4; ++mt)
            #pragma unroll
            for (int nt = 0; nt < 4; ++nt)
                acc[mt][nt] = __builtin_amdgcn_mfma_f32_16x16x32_bf16(
                    af[mt], bfr[nt], acc[mt][nt], 0, 0, 0);
    }

    #pragma unroll
    for (int mt = 0; mt < 4; ++mt) {
        #pragma unroll
        for (int nt = 0; nt < 4; ++nt) {
            const int n = n0 + wn + nt * 16 + l16;
            const int h = n >> 6, d = n & 63;
            #pragma unroll
            for (int r = 0; r < 4; ++r) {
                const int s = s0 + wm + mt * 16 + quad * 4 + r;
                Out[(((size_t)b * NHc + h) * Sc + s) * DKc + d] =
                    f2bf(acc[mt][nt][r]);
            }
        }
    }
}

// ---------------------------------------------------------------------------
// Kernel 2: row sums l_q = sum_{k<L} exp(s_qk), stored as 1/l.
// Main loop over full 16-key tiles (no per-element mask); masked tail tile.
// ---------------------------------------------------------------------------
__global__ __launch_bounds__(256) void rowsum_kernel(
    const int* __restrict__ L, float* __restrict__ ws)
{
    const int bh = blockIdx.x;
    const int b  = bh >> 4;
    const int Lb = L[b];
    const int wave = threadIdx.x >> 6;
    const int lane = threadIdx.x & 63;
    const int q0 = blockIdx.y * 128 + wave * 32;
    if (q0 >= Lb) return;

    const short* __restrict__ qarr = (const short*)(ws + QOFF) + (size_t)bh * Sc * DKc;
    const short* __restrict__ karr = (const short*)(ws + KOFF) + (size_t)bh * Sc * DKc;
    float* __restrict__ liarr = ws + LIOFF + (size_t)bh * Sc;

    const int l16 = lane & 15, quad = lane >> 4;

    const short* qrow0 = qarr + (size_t)(q0 + l16) * DKc;
    const short* qrow1 = qarr + (size_t)(q0 + 16 + l16) * DKc;
    const bf16x8 b0lo = *(const bf16x8*)(qrow0 + quad * 8);
    const bf16x8 b0hi = *(const bf16x8*)(qrow0 + 32 + quad * 8);
    const bf16x8 b1lo = *(const bf16x8*)(qrow1 + quad * 8);
    const bf16x8 b1hi = *(const bf16x8*)(qrow1 + 32 + quad * 8);

    float lacc0 = 0.f, lacc1 = 0.f;
    const int kfull = Lb & ~15;
    for (int k0 = 0; k0 < kfull; k0 += 16) {
        const short* krow = karr + (size_t)(k0 + l16) * DKc;
        const bf16x8 alo = *(const bf16x8*)(krow + quad * 8);
        const bf16x8 ahi = *(const bf16x8*)(krow + 32 + quad * 8);
        f32x4 c0 = {0.f, 0.f, 0.f, 0.f}, c1 = {0.f, 0.f, 0.f, 0.f};
        c0 = __builtin_amdgcn_mfma_f32_16x16x32_bf16(alo, b0lo, c0, 0, 0, 0);
        c0 = __builtin_amdgcn_mfma_f32_16x16x32_bf16(ahi, b0hi, c0, 0, 0, 0);
        c1 = __builtin_amdgcn_mfma_f32_16x16x32_bf16(alo, b1lo, c1, 0, 0, 0);
        c1 = __builtin_amdgcn_mfma_f32_16x16x32_bf16(ahi, b1hi, c1, 0, 0, 0);
        #pragma unroll
        for (int r = 0; r < 4; ++r) {
            lacc0 += __expf(c0[r]);
            lacc1 += __expf(c1[r]);
        }
    }
    if (kfull < Lb) {
        const int k0 = kfull;
        const short* krow = karr + (size_t)(k0 + l16) * DKc;
        const bf16x8 alo = *(const bf16x8*)(krow + quad * 8);
        const bf16x8 ahi = *(const bf16x8*)(krow + 32 + quad * 8);
        f32x4 c0 = {0.f, 0.f, 0.f, 0.f}, c1 = {0.f, 0.f, 0.f, 0.f};
        c0 = __builtin_amdgcn_mfma_f32_16x16x32_bf16(alo, b0lo, c0, 0, 0, 0);
        c0 = __builtin_amdgcn_mfma_f32_16x16x32_bf16(ahi, b0hi, c0, 0, 0, 0);
        c1 = __builtin_amdgcn_mfma_f32_16x16x32_bf16(alo, b1lo, c1, 0, 0, 0);
        c1 = __builtin_amdgcn_mfma_f32_16x16x32_bf16(ahi, b1hi, c1, 0, 0, 0);
        #pragma unroll
        for (int r = 0; r < 4; ++r) {
            if (k0 + quad * 4 + r < Lb) {
                lacc0 += __expf(c0[r]);
                lacc1 += __expf(c1[r]);
            }
        }
    }
    lacc0 += __shfl_xor(lacc0, 16, 64); lacc0 += __shfl_xor(lacc0, 32, 64);
    lacc1 += __shfl_xor(lacc1, 16, 64); lacc1 += __shfl_xor(lacc1, 32, 64);
    if (quad == 0 && q0 + l16 < Lb)      liarr[q0 + l16]      = 1.0f / lacc0;
    if (quad == 1 && q0 + 16 + l16 < Lb) liarr[q0 + 16 + l16] = 1.0f / lacc1;
}

// ---------------------------------------------------------------------------
// Kernel 3: attention column sums w[k] = sum_{q<L} exp(s_qk) / l_q.
// ---------------------------------------------------------------------------
__global__ __launch_bounds__(256) void colsum_kernel(
    const int* __restrict__ L, float* __restrict__ ws)
{
    const int bh = blockIdx.x;
    const int b  = bh >> 4;
    const int Lb = L[b];
    const int wave = threadIdx.x >> 6;
    const int lane = threadIdx.x & 63;
    const int k0 = blockIdx.y * 128 + wave * 32;
    if (k0 >= Lb) return;

    const short* __restrict__ qarr = (const short*)(ws + QOFF) + (size_t)bh * Sc * DKc;
    const short* __restrict__ karr = (const short*)(ws + KOFF) + (size_t)bh * Sc * DKc;
    const float* __restrict__ liarr = ws + LIOFF + (size_t)bh * Sc;
    float* __restrict__ warr = ws + WOFF + (size_t)bh * Sc;

    const int l16 = lane & 15, quad = lane >> 4;

    const short* krow0 = karr + (size_t)(k0 + l16) * DKc;
    const short* krow1 = karr + (size_t)(k0 + 16 + l16) * DKc;
    const bf16x8 a0lo = *(const bf16x8*)(krow0 + quad * 8);
    const bf16x8 a0hi = *(const bf16x8*)(krow0 + 32 + quad * 8);
    const bf16x8 a1lo = *(const bf16x8*)(krow1 + quad * 8);
    const bf16x8 a1hi = *(const bf16x8*)(krow1 + 32 + quad * 8);

    float w0[4] = {0.f, 0.f, 0.f, 0.f};
    float w1[4] = {0.f, 0.f, 0.f, 0.f};

    for (int q0 = 0; q0 < Lb; q0 += 16) {
        const short* qrow = qarr + (size_t)(q0 + l16) * DKc;
        const bf16x8 blo = *(const bf16x8*)(qrow + quad * 8);
        const bf16x8 bhi = *(const bf16x8*)(qrow + 32 + quad * 8);
        float lv = 0.f;
        if (q0 + l16 < Lb) lv = liarr[q0 + l16];
        f32x4 c0 = {0.f, 0.f, 0.f, 0.f}, c1 = {0.f, 0.f, 0.f, 0.f};
        c0 = __builtin_amdgcn_mfma_f32_16x16x32_bf16(a0lo, blo, c0, 0, 0, 0);
        c0 = __builtin_amdgcn_mfma_f32_16x16x32_bf16(a0hi, bhi, c0, 0, 0, 0);
        c1 = __builtin_amdgcn_mfma_f32_16x16x32_bf16(a1lo, blo, c1, 0, 0, 0);
        c1 = __builtin_amdgcn_mfma_f32_16x16x32_bf16(a1hi, bhi, c1, 0, 0, 0);
        #pragma unroll
        for (int r = 0; r < 4; ++r) {
            w0[r] += __expf(c0[r]) * lv;
            w1[r] += __expf(c1[r]) * lv;
        }
    }
    #pragma unroll
    for (int off = 1; off <= 8; off <<= 1) {
        #pragma unroll
        for (int r = 0; r < 4; ++r) {
            w0[r] += __shfl_xor(w0[r], off, 64);
            w1[r] += __shfl_xor(w1[r], off, 64);
        }
    }
    if (l16 == 0) {
        #pragma unroll
        for (int r = 0; r < 4; ++r) {
            const int ka = k0 + quad * 4 + r;
            if (ka < Lb) warr[ka] = w0[r];
            const int kb = k0 + 16 + quad * 4 + r;
            if (kb < Lb) warr[kb] = w1[r];
        }
    }
}

// ---------------------------------------------------------------------------
// Kernel 4a: partial y: yp[c][b,h,j] = sum_{s in chunk c} w[b,h,s]*x[b,s,j].
// Grid (16 j-chunks, 4 b, 16 s-chunks of 128) = 1024 blocks (4/CU).
// Padded s rows carry w=0, so the inner loop is a fixed 32 iterations.
// ---------------------------------------------------------------------------
__global__ __launch_bounds__(256) void yw_part_kernel(
    const float* __restrict__ x, const int* __restrict__ L,
    float* __restrict__ ws)
{
    const int b  = blockIdx.y;
    const int j0 = blockIdx.x * 64;
    const int s0 = blockIdx.z * 128;
    const int Lb = L[b];
    if (s0 >= Lb) return;
    const int js = threadIdx.x & 63;
    const int sl = threadIdx.x >> 6;
    const float* __restrict__ warr = ws + WOFF + (size_t)b * NHc * Sc;
    const float* __restrict__ xb = x + (size_t)b * Sc * Hc;

    __shared__ float wt[128][20];
    __shared__ float red[4][16][64];

    #pragma unroll
    for (int i = 0; i < 8; ++i) {
        const int s = (threadIdx.x & 15) + 16 * i;
        const int h = threadIdx.x >> 4;
        float v = 0.f;
        if (s0 + s < Lb) v = warr[(size_t)h * Sc + s0 + s];
        wt[s][h] = v;
    }
    __syncthreads();

    float acc[16];
    #pragma unroll
    for (int h = 0; h < 16; ++h) acc[h] = 0.f;

    #pragma unroll 4
    for (int s = sl; s < 128; s += 4) {
        const float xv = xb[(size_t)(s0 + s) * Hc + j0 + js];
        const f32x4 wa = *(const f32x4*)&wt[s][0];
        const f32x4 wb = *(const f32x4*)&wt[s][4];
        const f32x4 wc = *(const f32x4*)&wt[s][8];
        const f32x4 wd = *(const f32x4*)&wt[s][12];
        #pragma unroll
        for (int h = 0; h < 4; ++h) acc[h]      += wa[h] * xv;
        #pragma unroll
        for (int h = 0; h < 4; ++h) acc[4 + h]  += wb[h] * xv;
        #pragma unroll
        for (int h = 0; h < 4; ++h) acc[8 + h]  += wc[h] * xv;
        #pragma unroll
        for (int h = 0; h < 4; ++h) acc[12 + h] += wd[h] * xv;
    }
    #pragma unroll
    for (int h = 0; h < 16; ++h) red[sl][h][js] = acc[h];
    __syncthreads();
    if (sl == 0) {
        float* __restrict__ yp = ws + YPOFF +
            ((size_t)blockIdx.z * Bc * NHc + (size_t)b * NHc) * Hc;
        #pragma unroll
        for (int h = 0; h < 16; ++h)
            yp[(size_t)h * Hc + j0 + js] =
                red[0][h][js] + red[1][h][js] + red[2][h][js] + red[3][h][js];
    }
}

// ---------------------------------------------------------------------------
// Kernel 4b: y[b,h,j] = sum over valid chunks of yp. Chunks past L[b] were
// never written (poisoned) and are excluded by nc = ceil(L[b]/128).
// ---------------------------------------------------------------------------
__global__ __launch_bounds__(256) void yw_reduce_kernel(
    const int* __restrict__ L, float* __restrict__ ws)
{
    const int b = blockIdx.y;
    const int i = blockIdx.x * 256 + threadIdx.x;   // over NHc*Hc = 16384
    const int nc = (L[b] + 127) >> 7;
    const float* __restrict__ p = ws + YPOFF + (size_t)b * NHc * Hc + i;
    float acc = 0.f;
    for (int c = 0; c < nc; ++c)
        acc += p[(size_t)c * Bc * NHc * Hc];
    ws[YOFF + (size_t)b * NHc * Hc + i] = acc;
}

// ---------------------------------------------------------------------------
// Kernel 5: csum[b,n] = sum_j y[b,h(n),j]*Wv[n,j] + bv[n]*L[b].
// ---------------------------------------------------------------------------
__global__ __launch_bounds__(256) void csum_kernel(
    const float* __restrict__ Wv, const float* __restrict__ bv,
    const int* __restrict__ L, float* __restrict__ ws)
{
    const int b = blockIdx.y;
    const int n = blockIdx.x * 256 + threadIdx.x;
    const int h0 = (blockIdx.x * 256) >> 6;
    __shared__ float ys[4][1024];
    const float* __restrict__ y = ws + YOFF + ((size_t)b * NHc + h0) * Hc;
    for (int i = threadIdx.x; i < 4096; i += 256) ys[i >> 10][i & 1023] = y[i];
    __syncthreads();
    const int hl = threadIdx.x >> 6;
    const float* __restrict__ wrow = Wv + (size_t)n * Hc;
    float acc = 0.f;
    for (int j = 0; j < Hc; j += 4) {
        float4 wv = *(const float4*)(wrow + j);
        acc += wv.x*ys[hl][j] + wv.y*ys[hl][j+1] + wv.z*ys[hl][j+2] + wv.w*ys[hl][j+3];
    }
    ws[CSOFF + (size_t)b * Hc + n] = acc + bv[n] * (float)L[b];
}

// ---------------------------------------------------------------------------
// Kernel 6: pooled[b,o] = (sum_n csum[b,n]*Wo[o,n]) / L[b] + bo[o].
// ---------------------------------------------------------------------------
__global__ __launch_bounds__(256) void out_kernel(
    const float* __restrict__ Wo, const float* __restrict__ bo,
    const int* __restrict__ L, const float* __restrict__ ws,
    float* __restrict__ out)
{
    const int b = blockIdx.y;
    const int n = blockIdx.x * 256 + threadIdx.x;
    __shared__ float cs[Hc];
    const float* __restrict__ c = ws + CSOFF + (size_t)b * Hc;
    for (int i = threadIdx.x; i < Hc; i += 256) cs[i] = c[i];
    __syncthreads();
    const float* __restrict__ wrow = Wo + (size_t)n * Hc;
    float acc = 0.f;
    for (int h = 0; h < Hc; h += 4) {
        float4 wv = *(const float4*)(wrow + h);
        acc += wv.x*cs[h] + wv.y*cs[h+1] + wv.z*cs[h+2] + wv.w*cs[h+3];
    }
    out[(size_t)b * Hc + n] = acc / (float)L[b] + bo[n];
}

// ---------------------------------------------------------------------------
extern "C" void kernel_launch(void* const* d_in, const int* in_sizes, int n_in,
                              void* d_out, int out_size, void* d_ws, size_t ws_size,
                              hipStream_t stream)
{
    (void)in_sizes; (void)n_in; (void)out_size; (void)ws_size;
    const float* x  = (const float*)d_in[0];
    const int*   L  = (const int*)d_in[1];
    const float* Wq = (const float*)d_in[2];
    const float* Wk = (const float*)d_in[3];
    const float* Wv = (const float*)d_in[4];
    const float* bv = (const float*)d_in[5];
    const float* Wo = (const float*)d_in[6];
    const float* bo = (const float*)d_in[7];
    float* out = (float*)d_out;
    float* ws  = (float*)d_ws;

    cvt_kernel<<<4096, 256, 0, stream>>>(x,  (short*)(ws + XHOFF), 1.0f);
    cvt_kernel<<<512,  256, 0, stream>>>(Wq, (short*)(ws + WQOFF), 0.125f);
    cvt_kernel<<<512,  256, 0, stream>>>(Wk, (short*)(ws + WKOFF), 1.0f);

    dim3 gp(Hc / 128, (Bc * Sc) / 128, 2);
    proj_mfma_kernel<<<gp, 256, 0, stream>>>(L, ws);

    dim3 gr(Bc * NHc, Sc / 128);
    rowsum_kernel<<<gr, 256, 0, stream>>>(L, ws);
    colsum_kernel<<<gr, 256, 0, stream>>>(L, ws);

    dim3 gy(Hc / 64, Bc, Sc / 128);
    yw_part_kernel<<<gy, 256, 0, stream>>>(x, L, ws);

    dim3 gyr((NHc * Hc) / 256, Bc);
    yw_reduce_kernel<<<gyr, 256, 0, stream>>>(L, ws);

    dim3 gc(Hc / 256, Bc);
    csum_kernel<<<gc, 256, 0, stream>>>(Wv, bv, L, ws);

    dim3 go(Hc / 256, Bc);
    out_kernel<<<go, 256, 0, stream>>>(Wo, bo, L, ws, out);
}

// Round 5
// 340.000 us; speedup vs baseline: 8.0983x; 1.2136x over previous
//
#include <hip/hip_runtime.h>
#include <hip/hip_bf16.h>
#include <math.h>

// Problem constants (B,S,H fixed by setup_inputs)
constexpr int Bc = 4, Sc = 2048, Hc = 1024, NHc = 16, DKc = 64;

// Workspace layout (float units). Total ~61 MB.
constexpr size_t XHOFF = 0;                 // x bf16: 8,388,608 shorts
constexpr size_t QOFF  = 4194304;           // Q bf16 (bh,s,d)
constexpr size_t KOFF  = 8388608;           // K bf16 (bh,s,d)
constexpr size_t WQOFF = 12582912;          // Wq bf16 (pre-scaled 0.125)
constexpr size_t WKOFF = 13107200;          // Wk bf16
constexpr size_t LIOFF = 13631488;          // 1/rowsum per (bh,q)
constexpr size_t WOFF  = 13762560;          // attn column sums per (bh,k)
constexpr size_t YOFF  = 13893632;          // y[b,h,j] fp32 (4*16*1024)
constexpr size_t CSOFF = 13959168;          // csum[b,n] (4*1024)
constexpr size_t YPOFF = 13963264;          // y partials: 16 chunks x 65536
constexpr size_t RPOFF = 15011840;          // rowsum partials: 4*64*2048
constexpr size_t CPOFF = 15536128;          // colsum partials: 4*64*2048

typedef __attribute__((ext_vector_type(8))) short bf16x8;  // 8 bf16 (4 VGPRs)
typedef __attribute__((ext_vector_type(4))) float f32x4;

__device__ inline short f2bf(float v) {
    __hip_bfloat16 h = __float2bfloat16(v);
    return *reinterpret_cast<short*>(&h);
}

__device__ inline void gld_lds16(const void* g, void* l) {
    __builtin_amdgcn_global_load_lds(
        (const __attribute__((address_space(1))) unsigned int*)g,
        (__attribute__((address_space(3))) unsigned int*)l, 16, 0, 0);
}

// ---------------------------------------------------------------------------
// Kernel 0: fp32 -> bf16 conversion (8 elems/thread, packed 16B store).
// ---------------------------------------------------------------------------
__global__ __launch_bounds__(256) void cvt_kernel(
    const float* __restrict__ src, short* __restrict__ dst, float scale)
{
    const size_t i = ((size_t)blockIdx.x * 256 + threadIdx.x) * 8;
    float4 a = *(const float4*)(src + i);
    float4 b = *(const float4*)(src + i + 4);
    bf16x8 o;
    o[0] = f2bf(a.x * scale); o[1] = f2bf(a.y * scale);
    o[2] = f2bf(a.z * scale); o[3] = f2bf(a.w * scale);
    o[4] = f2bf(b.x * scale); o[5] = f2bf(b.y * scale);
    o[6] = f2bf(b.z * scale); o[7] = f2bf(b.w * scale);
    *(bf16x8*)(dst + i) = o;
}

// ---------------------------------------------------------------------------
// Kernel 1: Q/K projections, bf16 MFMA, m97-style 128x128 tile.
// z=0: Q (Wq pre-scaled), z=1: K. Out layout (b,h,s,d) bf16.
// ---------------------------------------------------------------------------
__global__ __launch_bounds__(256) void proj_mfma_kernel(
    const int* __restrict__ L, float* __restrict__ ws)
{
    const int z  = blockIdx.z;
    const int m0 = blockIdx.y * 128;
    const int n0 = blockIdx.x * 128;
    const int b  = m0 >> 11;
    const int s0 = m0 & 2047;
    const int Lb = L[b];
    if (s0 >= Lb) return;

    const short* __restrict__ A = (const short*)(ws + XHOFF);
    const short* __restrict__ W = (const short*)(ws + (z == 0 ? WQOFF : WKOFF));
    short* __restrict__ Out = (short*)(ws + (z == 0 ? QOFF : KOFF));

    __shared__ __align__(16) short As[128 * 32];
    __shared__ __align__(16) short Bs[128 * 32];

    const int tid  = threadIdx.x;
    const int lane = tid & 63;
    const int wave = tid >> 6;
    const int l16  = lane & 15, quad = lane >> 4;
    const int wm = (wave & 1) * 64, wn = (wave >> 1) * 64;

    const int c0 = tid, c1 = tid + 256;
    const int r0 = c0 >> 2, g0 = (c0 & 3) * 8;
    const int r1 = c1 >> 2, g1 = (c1 & 3) * 8;
    short* lA0 = As + wave * 512;
    short* lA1 = As + 2048 + wave * 512;
    short* lB0 = Bs + wave * 512;
    short* lB1 = Bs + 2048 + wave * 512;

    const f32x4 z4 = {0.f, 0.f, 0.f, 0.f};
    f32x4 acc[4][4];
    #pragma unroll
    for (int i = 0; i < 4; ++i)
        #pragma unroll
        for (int j = 0; j < 4; ++j) acc[i][j] = z4;

    for (int k0 = 0; k0 < Hc; k0 += 32) {
        __syncthreads();
        gld_lds16(A + (size_t)(m0 + r0) * Hc + k0 + g0, lA0);
        gld_lds16(A + (size_t)(m0 + r1) * Hc + k0 + g1, lA1);
        gld_lds16(W + (size_t)(n0 + r0) * Hc + k0 + g0, lB0);
        gld_lds16(W + (size_t)(n0 + r1) * Hc + k0 + g1, lB1);
        __syncthreads();

        bf16x8 af[4], bfr[4];
        #pragma unroll
        for (int mt = 0; mt < 4; ++mt)
            af[mt] = *(const bf16x8*)(As + (wm + mt * 16 + l16) * 32 + quad * 8);
        #pragma unroll
        for (int nt = 0; nt < 4; ++nt)
            bfr[nt] = *(const bf16x8*)(Bs + (wn + nt * 16 + l16) * 32 + quad * 8);
        #pragma unroll
        for (int mt = 0; mt < 4; ++mt)
            #pragma unroll
            for (int nt = 0; nt < 4; ++nt)
                acc[mt][nt] = __builtin_amdgcn_mfma_f32_16x16x32_bf16(
                    af[mt], bfr[nt], acc[mt][nt], 0, 0, 0);
    }

    #pragma unroll
    for (int mt = 0; mt < 4; ++mt) {
        #pragma unroll
        for (int nt = 0; nt < 4; ++nt) {
            const int n = n0 + wn + nt * 16 + l16;
            const int h = n >> 6, d = n & 63;
            #pragma unroll
            for (int r = 0; r < 4; ++r) {
                const int s = s0 + wm + mt * 16 + quad * 4 + r;
                Out[(((size_t)b * NHc + h) * Sc + s) * DKc + d] =
                    f2bf(acc[mt][nt][r]);
            }
        }
    }
}

// ---------------------------------------------------------------------------
// Kernel 2a: partial row sums over a 512-key chunk.
// rp[c][bh][q] = sum_{k in chunk c, k<L} exp(s_qk).
// ---------------------------------------------------------------------------
__global__ __launch_bounds__(256) void rowsum_part_kernel(
    const int* __restrict__ L, float* __restrict__ ws)
{
    const int bh = blockIdx.x;
    const int b  = bh >> 4;
    const int Lb = L[b];
    const int kc0 = blockIdx.z * 512;
    const int wave = threadIdx.x >> 6;
    const int lane = threadIdx.x & 63;
    const int q0 = blockIdx.y * 128 + wave * 32;
    if (q0 >= Lb || kc0 >= Lb) return;

    const short* __restrict__ qarr = (const short*)(ws + QOFF) + (size_t)bh * Sc * DKc;
    const short* __restrict__ karr = (const short*)(ws + KOFF) + (size_t)bh * Sc * DKc;

    const int l16 = lane & 15, quad = lane >> 4;

    const short* qrow0 = qarr + (size_t)(q0 + l16) * DKc;
    const short* qrow1 = qarr + (size_t)(q0 + 16 + l16) * DKc;
    const bf16x8 b0lo = *(const bf16x8*)(qrow0 + quad * 8);
    const bf16x8 b0hi = *(const bf16x8*)(qrow0 + 32 + quad * 8);
    const bf16x8 b1lo = *(const bf16x8*)(qrow1 + quad * 8);
    const bf16x8 b1hi = *(const bf16x8*)(qrow1 + 32 + quad * 8);

    const int kend  = (kc0 + 512 < Lb) ? kc0 + 512 : Lb;
    const int kfull = kc0 + ((kend - kc0) & ~15);

    float lacc0 = 0.f, lacc1 = 0.f;
    for (int k0 = kc0; k0 < kfull; k0 += 16) {
        const short* krow = karr + (size_t)(k0 + l16) * DKc;
        const bf16x8 alo = *(const bf16x8*)(krow + quad * 8);
        const bf16x8 ahi = *(const bf16x8*)(krow + 32 + quad * 8);
        f32x4 c0 = {0.f, 0.f, 0.f, 0.f}, c1 = {0.f, 0.f, 0.f, 0.f};
        c0 = __builtin_amdgcn_mfma_f32_16x16x32_bf16(alo, b0lo, c0, 0, 0, 0);
        c0 = __builtin_amdgcn_mfma_f32_16x16x32_bf16(ahi, b0hi, c0, 0, 0, 0);
        c1 = __builtin_amdgcn_mfma_f32_16x16x32_bf16(alo, b1lo, c1, 0, 0, 0);
        c1 = __builtin_amdgcn_mfma_f32_16x16x32_bf16(ahi, b1hi, c1, 0, 0, 0);
        #pragma unroll
        for (int r = 0; r < 4; ++r) {
            lacc0 += __expf(c0[r]);
            lacc1 += __expf(c1[r]);
        }
    }
    if (kfull < kend) {
        const int k0 = kfull;
        const short* krow = karr + (size_t)(k0 + l16) * DKc;
        const bf16x8 alo = *(const bf16x8*)(krow + quad * 8);
        const bf16x8 ahi = *(const bf16x8*)(krow + 32 + quad * 8);
        f32x4 c0 = {0.f, 0.f, 0.f, 0.f}, c1 = {0.f, 0.f, 0.f, 0.f};
        c0 = __builtin_amdgcn_mfma_f32_16x16x32_bf16(alo, b0lo, c0, 0, 0, 0);
        c0 = __builtin_amdgcn_mfma_f32_16x16x32_bf16(ahi, b0hi, c0, 0, 0, 0);
        c1 = __builtin_amdgcn_mfma_f32_16x16x32_bf16(alo, b1lo, c1, 0, 0, 0);
        c1 = __builtin_amdgcn_mfma_f32_16x16x32_bf16(ahi, b1hi, c1, 0, 0, 0);
        #pragma unroll
        for (int r = 0; r < 4; ++r) {
            if (k0 + quad * 4 + r < kend) {
                lacc0 += __expf(c0[r]);
                lacc1 += __expf(c1[r]);
            }
        }
    }
    lacc0 += __shfl_xor(lacc0, 16, 64); lacc0 += __shfl_xor(lacc0, 32, 64);
    lacc1 += __shfl_xor(lacc1, 16, 64); lacc1 += __shfl_xor(lacc1, 32, 64);
    float* __restrict__ rp = ws + RPOFF + ((size_t)blockIdx.z * 64 + bh) * Sc;
    if (quad == 0) rp[q0 + l16]      = lacc0;
    if (quad == 1) rp[q0 + 16 + l16] = lacc1;
}

// ---------------------------------------------------------------------------
// Kernel 2b: liarr[q] = 1 / sum over valid k-chunks of rp.
// ---------------------------------------------------------------------------
__global__ __launch_bounds__(256) void rowsum_reduce_kernel(
    const int* __restrict__ L, float* __restrict__ ws)
{
    const int bh = blockIdx.y;
    const int q  = blockIdx.x * 256 + threadIdx.x;
    const int nc = (L[bh >> 4] + 511) >> 9;
    float acc = 0.f;
    for (int c = 0; c < nc; ++c)
        acc += ws[RPOFF + ((size_t)c * 64 + bh) * Sc + q];
    ws[LIOFF + (size_t)bh * Sc + q] = 1.0f / acc;
}

// ---------------------------------------------------------------------------
// Kernel 3a: partial column sums over a 512-query chunk.
// cp[c][bh][k] = sum_{q in chunk c, q<L} exp(s_qk) / l_q.
// ---------------------------------------------------------------------------
__global__ __launch_bounds__(256) void colsum_part_kernel(
    const int* __restrict__ L, float* __restrict__ ws)
{
    const int bh = blockIdx.x;
    const int b  = bh >> 4;
    const int Lb = L[b];
    const int qc0 = blockIdx.z * 512;
    const int wave = threadIdx.x >> 6;
    const int lane = threadIdx.x & 63;
    const int k0 = blockIdx.y * 128 + wave * 32;
    if (k0 >= Lb || qc0 >= Lb) return;

    const short* __restrict__ qarr = (const short*)(ws + QOFF) + (size_t)bh * Sc * DKc;
    const short* __restrict__ karr = (const short*)(ws + KOFF) + (size_t)bh * Sc * DKc;
    const float* __restrict__ liarr = ws + LIOFF + (size_t)bh * Sc;

    const int l16 = lane & 15, quad = lane >> 4;

    const short* krow0 = karr + (size_t)(k0 + l16) * DKc;
    const short* krow1 = karr + (size_t)(k0 + 16 + l16) * DKc;
    const bf16x8 a0lo = *(const bf16x8*)(krow0 + quad * 8);
    const bf16x8 a0hi = *(const bf16x8*)(krow0 + 32 + quad * 8);
    const bf16x8 a1lo = *(const bf16x8*)(krow1 + quad * 8);
    const bf16x8 a1hi = *(const bf16x8*)(krow1 + 32 + quad * 8);

    const int qend  = (qc0 + 512 < Lb) ? qc0 + 512 : Lb;
    const int qfull = qc0 + ((qend - qc0) & ~15);

    float w0[4] = {0.f, 0.f, 0.f, 0.f};
    float w1[4] = {0.f, 0.f, 0.f, 0.f};

    for (int q0 = qc0; q0 < qfull; q0 += 16) {
        const short* qrow = qarr + (size_t)(q0 + l16) * DKc;
        const bf16x8 blo = *(const bf16x8*)(qrow + quad * 8);
        const bf16x8 bhi = *(const bf16x8*)(qrow + 32 + quad * 8);
        const float lv = liarr[q0 + l16];
        f32x4 c0 = {0.f, 0.f, 0.f, 0.f}, c1 = {0.f, 0.f, 0.f, 0.f};
        c0 = __builtin_amdgcn_mfma_f32_16x16x32_bf16(a0lo, blo, c0, 0, 0, 0);
        c0 = __builtin_amdgcn_mfma_f32_16x16x32_bf16(a0hi, bhi, c0, 0, 0, 0);
        c1 = __builtin_amdgcn_mfma_f32_16x16x32_bf16(a1lo, blo, c1, 0, 0, 0);
        c1 = __builtin_amdgcn_mfma_f32_16x16x32_bf16(a1hi, bhi, c1, 0, 0, 0);
        #pragma unroll
        for (int r = 0; r < 4; ++r) {
            w0[r] += __expf(c0[r]) * lv;
            w1[r] += __expf(c1[r]) * lv;
        }
    }
    if (qfull < qend) {
        const int q0 = qfull;
        const short* qrow = qarr + (size_t)(q0 + l16) * DKc;
        const bf16x8 blo = *(const bf16x8*)(qrow + quad * 8);
        const bf16x8 bhi = *(const bf16x8*)(qrow + 32 + quad * 8);
        const float lv = (q0 + l16 < qend) ? liarr[q0 + l16] : 0.f;
        f32x4 c0 = {0.f, 0.f, 0.f, 0.f}, c1 = {0.f, 0.f, 0.f, 0.f};
        c0 = __builtin_amdgcn_mfma_f32_16x16x32_bf16(a0lo, blo, c0, 0, 0, 0);
        c0 = __builtin_amdgcn_mfma_f32_16x16x32_bf16(a0hi, bhi, c0, 0, 0, 0);
        c1 = __builtin_amdgcn_mfma_f32_16x16x32_bf16(a1lo, blo, c1, 0, 0, 0);
        c1 = __builtin_amdgcn_mfma_f32_16x16x32_bf16(a1hi, bhi, c1, 0, 0, 0);
        #pragma unroll
        for (int r = 0; r < 4; ++r) {
            w0[r] += __expf(c0[r]) * lv;
            w1[r] += __expf(c1[r]) * lv;
        }
    }
    #pragma unroll
    for (int off = 1; off <= 8; off <<= 1) {
        #pragma unroll
        for (int r = 0; r < 4; ++r) {
            w0[r] += __shfl_xor(w0[r], off, 64);
            w1[r] += __shfl_xor(w1[r], off, 64);
        }
    }
    if (l16 == 0) {
        float* __restrict__ cp = ws + CPOFF + ((size_t)blockIdx.z * 64 + bh) * Sc;
        #pragma unroll
        for (int r = 0; r < 4; ++r) {
            cp[k0 + quad * 4 + r]      = w0[r];
            cp[k0 + 16 + quad * 4 + r] = w1[r];
        }
    }
}

// ---------------------------------------------------------------------------
// Kernel 3b: warr[k] = sum over valid q-chunks of cp.
// ---------------------------------------------------------------------------
__global__ __launch_bounds__(256) void colsum_reduce_kernel(
    const int* __restrict__ L, float* __restrict__ ws)
{
    const int bh = blockIdx.y;
    const int k  = blockIdx.x * 256 + threadIdx.x;
    const int nc = (L[bh >> 4] + 511) >> 9;
    float acc = 0.f;
    for (int c = 0; c < nc; ++c)
        acc += ws[CPOFF + ((size_t)c * 64 + bh) * Sc + k];
    ws[WOFF + (size_t)bh * Sc + k] = acc;
}

// ---------------------------------------------------------------------------
// Kernel 4a: partial y: yp[c][b,h,j] = sum_{s in chunk c} w[b,h,s]*x[b,s,j].
// ---------------------------------------------------------------------------
__global__ __launch_bounds__(256) void yw_part_kernel(
    const float* __restrict__ x, const int* __restrict__ L,
    float* __restrict__ ws)
{
    const int b  = blockIdx.y;
    const int j0 = blockIdx.x * 64;
    const int s0 = blockIdx.z * 128;
    const int Lb = L[b];
    if (s0 >= Lb) return;
    const int js = threadIdx.x & 63;
    const int sl = threadIdx.x >> 6;
    const float* __restrict__ warr = ws + WOFF + (size_t)b * NHc * Sc;
    const float* __restrict__ xb = x + (size_t)b * Sc * Hc;

    __shared__ float wt[128][20];
    __shared__ float red[4][16][64];

    #pragma unroll
    for (int i = 0; i < 8; ++i) {
        const int s = (threadIdx.x & 15) + 16 * i;
        const int h = threadIdx.x >> 4;
        float v = 0.f;
        if (s0 + s < Lb) v = warr[(size_t)h * Sc + s0 + s];
        wt[s][h] = v;
    }
    __syncthreads();

    float acc[16];
    #pragma unroll
    for (int h = 0; h < 16; ++h) acc[h] = 0.f;

    #pragma unroll 4
    for (int s = sl; s < 128; s += 4) {
        const float xv = xb[(size_t)(s0 + s) * Hc + j0 + js];
        const f32x4 wa = *(const f32x4*)&wt[s][0];
        const f32x4 wb = *(const f32x4*)&wt[s][4];
        const f32x4 wc = *(const f32x4*)&wt[s][8];
        const f32x4 wd = *(const f32x4*)&wt[s][12];
        #pragma unroll
        for (int h = 0; h < 4; ++h) acc[h]      += wa[h] * xv;
        #pragma unroll
        for (int h = 0; h < 4; ++h) acc[4 + h]  += wb[h] * xv;
        #pragma unroll
        for (int h = 0; h < 4; ++h) acc[8 + h]  += wc[h] * xv;
        #pragma unroll
        for (int h = 0; h < 4; ++h) acc[12 + h] += wd[h] * xv;
    }
    #pragma unroll
    for (int h = 0; h < 16; ++h) red[sl][h][js] = acc[h];
    __syncthreads();
    if (sl == 0) {
        float* __restrict__ yp = ws + YPOFF +
            ((size_t)blockIdx.z * Bc * NHc + (size_t)b * NHc) * Hc;
        #pragma unroll
        for (int h = 0; h < 16; ++h)
            yp[(size_t)h * Hc + j0 + js] =
                red[0][h][js] + red[1][h][js] + red[2][h][js] + red[3][h][js];
    }
}

// ---------------------------------------------------------------------------
// Kernel 4b: y[b,h,j] = sum over valid chunks of yp.
// ---------------------------------------------------------------------------
__global__ __launch_bounds__(256) void yw_reduce_kernel(
    const int* __restrict__ L, float* __restrict__ ws)
{
    const int b = blockIdx.y;
    const int i = blockIdx.x * 256 + threadIdx.x;   // over NHc*Hc = 16384
    const int nc = (L[b] + 127) >> 7;
    const float* __restrict__ p = ws + YPOFF + (size_t)b * NHc * Hc + i;
    float acc = 0.f;
    for (int c = 0; c < nc; ++c)
        acc += p[(size_t)c * Bc * NHc * Hc];
    ws[YOFF + (size_t)b * NHc * Hc + i] = acc;
}

// ---------------------------------------------------------------------------
// Kernel 5: csum[b,n] = sum_j y[b,h(n),j]*Wv[n,j] + bv[n]*L[b].
// ---------------------------------------------------------------------------
__global__ __launch_bounds__(256) void csum_kernel(
    const float* __restrict__ Wv, const float* __restrict__ bv,
    const int* __restrict__ L, float* __restrict__ ws)
{
    const int b = blockIdx.y;
    const int n = blockIdx.x * 256 + threadIdx.x;
    const int h0 = (blockIdx.x * 256) >> 6;
    __shared__ float ys[4][1024];
    const float* __restrict__ y = ws + YOFF + ((size_t)b * NHc + h0) * Hc;
    for (int i = threadIdx.x; i < 4096; i += 256) ys[i >> 10][i & 1023] = y[i];
    __syncthreads();
    const int hl = threadIdx.x >> 6;
    const float* __restrict__ wrow = Wv + (size_t)n * Hc;
    float acc = 0.f;
    for (int j = 0; j < Hc; j += 4) {
        float4 wv = *(const float4*)(wrow + j);
        acc += wv.x*ys[hl][j] + wv.y*ys[hl][j+1] + wv.z*ys[hl][j+2] + wv.w*ys[hl][j+3];
    }
    ws[CSOFF + (size_t)b * Hc + n] = acc + bv[n] * (float)L[b];
}

// ---------------------------------------------------------------------------
// Kernel 6: pooled[b,o] = (sum_n csum[b,n]*Wo[o,n]) / L[b] + bo[o].
// ---------------------------------------------------------------------------
__global__ __launch_bounds__(256) void out_kernel(
    const float* __restrict__ Wo, const float* __restrict__ bo,
    const int* __restrict__ L, const float* __restrict__ ws,
    float* __restrict__ out)
{
    const int b = blockIdx.y;
    const int n = blockIdx.x * 256 + threadIdx.x;
    __shared__ float cs[Hc];
    const float* __restrict__ c = ws + CSOFF + (size_t)b * Hc;
    for (int i = threadIdx.x; i < Hc; i += 256) cs[i] = c[i];
    __syncthreads();
    const float* __restrict__ wrow = Wo + (size_t)n * Hc;
    float acc = 0.f;
    for (int h = 0; h < Hc; h += 4) {
        float4 wv = *(const float4*)(wrow + h);
        acc += wv.x*cs[h] + wv.y*cs[h+1] + wv.z*cs[h+2] + wv.w*cs[h+3];
    }
    out[(size_t)b * Hc + n] = acc / (float)L[b] + bo[n];
}

// ---------------------------------------------------------------------------
extern "C" void kernel_launch(void* const* d_in, const int* in_sizes, int n_in,
                              void* d_out, int out_size, void* d_ws, size_t ws_size,
                              hipStream_t stream)
{
    (void)in_sizes; (void)n_in; (void)out_size; (void)ws_size;
    const float* x  = (const float*)d_in[0];
    const int*   L  = (const int*)d_in[1];
    const float* Wq = (const float*)d_in[2];
    const float* Wk = (const float*)d_in[3];
    const float* Wv = (const float*)d_in[4];
    const float* bv = (const float*)d_in[5];
    const float* Wo = (const float*)d_in[6];
    const float* bo = (const float*)d_in[7];
    float* out = (float*)d_out;
    float* ws  = (float*)d_ws;

    cvt_kernel<<<4096, 256, 0, stream>>>(x,  (short*)(ws + XHOFF), 1.0f);
    cvt_kernel<<<512,  256, 0, stream>>>(Wq, (short*)(ws + WQOFF), 0.125f);
    cvt_kernel<<<512,  256, 0, stream>>>(Wk, (short*)(ws + WKOFF), 1.0f);

    dim3 gp(Hc / 128, (Bc * Sc) / 128, 2);
    proj_mfma_kernel<<<gp, 256, 0, stream>>>(L, ws);

    dim3 gr(Bc * NHc, Sc / 128, 4);
    rowsum_part_kernel<<<gr, 256, 0, stream>>>(L, ws);
    dim3 grr(Sc / 256, Bc * NHc);
    rowsum_reduce_kernel<<<grr, 256, 0, stream>>>(L, ws);

    dim3 gcp(Bc * NHc, Sc / 128, 4);
    colsum_part_kernel<<<gcp, 256, 0, stream>>>(L, ws);
    colsum_reduce_kernel<<<grr, 256, 0, stream>>>(L, ws);

    dim3 gy(Hc / 64, Bc, Sc / 128);
    yw_part_kernel<<<gy, 256, 0, stream>>>(x, L, ws);

    dim3 gyr((NHc * Hc) / 256, Bc);
    yw_reduce_kernel<<<gyr, 256, 0, stream>>>(L, ws);

    dim3 gc(Hc / 256, Bc);
    csum_kernel<<<gc, 256, 0, stream>>>(Wv, bv, L, ws);

    dim3 go(Hc / 256, Bc);
    out_kernel<<<go, 256, 0, stream>>>(Wo, bo, L, ws, out);
}

// Round 6
// 276.542 us; speedup vs baseline: 9.9566x; 1.2295x over previous
//
#include <hip/hip_runtime.h>
#include <hip/hip_bf16.h>
#include <math.h>

// Problem constants (B,S,H fixed by setup_inputs)
constexpr int Bc = 4, Sc = 2048, Hc = 1024, NHc = 16, DKc = 64;

// Workspace layout (float units). Total ~61 MB.
constexpr size_t XHOFF = 0;                 // x bf16: 8,388,608 shorts
constexpr size_t QOFF  = 4194304;           // Q bf16 (bh,s,d)
constexpr size_t KOFF  = 8388608;           // K bf16 (bh,s,d)
constexpr size_t WQOFF = 12582912;          // Wq bf16 (pre-scaled 0.125)
constexpr size_t WKOFF = 13107200;          // Wk bf16
constexpr size_t LIOFF = 13631488;          // 1/rowsum per (bh,q)
constexpr size_t WOFF  = 13762560;          // attn column sums per (bh,k)
constexpr size_t YOFF  = 13893632;          // y[b,h,j] fp32 (4*16*1024)
constexpr size_t CSOFF = 13959168;          // csum[b,n] (4*1024)
constexpr size_t YPOFF = 13963264;          // y partials: 16 chunks x 65536
constexpr size_t RPOFF = 15011840;          // rowsum partials: 4*64*2048
constexpr size_t CPOFF = 15536128;          // colsum partials: 4*64*2048

typedef __attribute__((ext_vector_type(8))) short bf16x8;  // 8 bf16 (4 VGPRs)
typedef __attribute__((ext_vector_type(4))) float f32x4;

__device__ inline short f2bf(float v) {
    __hip_bfloat16 h = __float2bfloat16(v);
    return *reinterpret_cast<short*>(&h);
}

__device__ inline void gld_lds16(const void* g, void* l) {
    __builtin_amdgcn_global_load_lds(
        (const __attribute__((address_space(1))) unsigned int*)g,
        (__attribute__((address_space(3))) unsigned int*)l, 16, 0, 0);
}

// ---------------------------------------------------------------------------
// Kernel 0: fp32 -> bf16 conversion (8 elems/thread, packed 16B store).
// ---------------------------------------------------------------------------
__global__ __launch_bounds__(256) void cvt_kernel(
    const float* __restrict__ src, short* __restrict__ dst, float scale)
{
    const size_t i = ((size_t)blockIdx.x * 256 + threadIdx.x) * 8;
    float4 a = *(const float4*)(src + i);
    float4 b = *(const float4*)(src + i + 4);
    bf16x8 o;
    o[0] = f2bf(a.x * scale); o[1] = f2bf(a.y * scale);
    o[2] = f2bf(a.z * scale); o[3] = f2bf(a.w * scale);
    o[4] = f2bf(b.x * scale); o[5] = f2bf(b.y * scale);
    o[6] = f2bf(b.z * scale); o[7] = f2bf(b.w * scale);
    *(bf16x8*)(dst + i) = o;
}

// ---------------------------------------------------------------------------
// Kernel 1: Q/K projections, bf16 MFMA, m97-style 128x128 tile.
// ---------------------------------------------------------------------------
__global__ __launch_bounds__(256) void proj_mfma_kernel(
    const int* __restrict__ L, float* __restrict__ ws)
{
    const int z  = blockIdx.z;
    const int m0 = blockIdx.y * 128;
    const int n0 = blockIdx.x * 128;
    const int b  = m0 >> 11;
    const int s0 = m0 & 2047;
    const int Lb = L[b];
    if (s0 >= Lb) return;

    const short* __restrict__ A = (const short*)(ws + XHOFF);
    const short* __restrict__ W = (const short*)(ws + (z == 0 ? WQOFF : WKOFF));
    short* __restrict__ Out = (short*)(ws + (z == 0 ? QOFF : KOFF));

    __shared__ __align__(16) short As[128 * 32];
    __shared__ __align__(16) short Bs[128 * 32];

    const int tid  = threadIdx.x;
    const int lane = tid & 63;
    const int wave = tid >> 6;
    const int l16  = lane & 15, quad = lane >> 4;
    const int wm = (wave & 1) * 64, wn = (wave >> 1) * 64;

    const int c0 = tid, c1 = tid + 256;
    const int r0 = c0 >> 2, g0 = (c0 & 3) * 8;
    const int r1 = c1 >> 2, g1 = (c1 & 3) * 8;
    short* lA0 = As + wave * 512;
    short* lA1 = As + 2048 + wave * 512;
    short* lB0 = Bs + wave * 512;
    short* lB1 = Bs + 2048 + wave * 512;

    const f32x4 z4 = {0.f, 0.f, 0.f, 0.f};
    f32x4 acc[4][4];
    #pragma unroll
    for (int i = 0; i < 4; ++i)
        #pragma unroll
        for (int j = 0; j < 4; ++j) acc[i][j] = z4;

    for (int k0 = 0; k0 < Hc; k0 += 32) {
        __syncthreads();
        gld_lds16(A + (size_t)(m0 + r0) * Hc + k0 + g0, lA0);
        gld_lds16(A + (size_t)(m0 + r1) * Hc + k0 + g1, lA1);
        gld_lds16(W + (size_t)(n0 + r0) * Hc + k0 + g0, lB0);
        gld_lds16(W + (size_t)(n0 + r1) * Hc + k0 + g1, lB1);
        __syncthreads();

        bf16x8 af[4], bfr[4];
        #pragma unroll
        for (int mt = 0; mt < 4; ++mt)
            af[mt] = *(const bf16x8*)(As + (wm + mt * 16 + l16) * 32 + quad * 8);
        #pragma unroll
        for (int nt = 0; nt < 4; ++nt)
            bfr[nt] = *(const bf16x8*)(Bs + (wn + nt * 16 + l16) * 32 + quad * 8);
        #pragma unroll
        for (int mt = 0; mt < 4; ++mt)
            #pragma unroll
            for (int nt = 0; nt < 4; ++nt)
                acc[mt][nt] = __builtin_amdgcn_mfma_f32_16x16x32_bf16(
                    af[mt], bfr[nt], acc[mt][nt], 0, 0, 0);
    }

    #pragma unroll
    for (int mt = 0; mt < 4; ++mt) {
        #pragma unroll
        for (int nt = 0; nt < 4; ++nt) {
            const int n = n0 + wn + nt * 16 + l16;
            const int h = n >> 6, d = n & 63;
            #pragma unroll
            for (int r = 0; r < 4; ++r) {
                const int s = s0 + wm + mt * 16 + quad * 4 + r;
                Out[(((size_t)b * NHc + h) * Sc + s) * DKc + d] =
                    f2bf(acc[mt][nt][r]);
            }
        }
    }
}

// ---------------------------------------------------------------------------
// Kernel 2a: partial row sums over a 512-key chunk, LDS-staged K stream.
// Block: (bh, q-tile of 128 = 4 waves x 32 q, k-chunk of 512).
// K tiles of 64 rows staged via global_load_lds with XOR-swizzled chunk
// placement (slot = row*8 + (c ^ (row&7))) so ds_read_b128 frags are 2-way.
// ---------------------------------------------------------------------------
__global__ __launch_bounds__(256) void rowsum_part_kernel(
    const int* __restrict__ L, float* __restrict__ ws)
{
    const int bh = blockIdx.x;
    const int b  = bh >> 4;
    const int Lb = L[b];
    const int kc0 = blockIdx.z * 512;
    if (blockIdx.y * 128 >= Lb || kc0 >= Lb) return;   // block-uniform exit

    const int tid  = threadIdx.x;
    const int wave = tid >> 6;
    const int lane = tid & 63;
    const int q0 = blockIdx.y * 128 + wave * 32;
    const int l16 = lane & 15, quad = lane >> 4;

    const short* __restrict__ qarr = (const short*)(ws + QOFF) + (size_t)bh * Sc * DKc;
    const short* __restrict__ karr = (const short*)(ws + KOFF) + (size_t)bh * Sc * DKc;

    __shared__ __align__(16) short Ks[64 * 64];   // 8 KB, swizzled slots

    // Q fragments (fixed for the whole chunk), straight from global.
    const short* qrow0 = qarr + (size_t)(q0 + l16) * DKc;
    const short* qrow1 = qarr + (size_t)(q0 + 16 + l16) * DKc;
    const bf16x8 b0lo = *(const bf16x8*)(qrow0 + quad * 8);
    const bf16x8 b0hi = *(const bf16x8*)(qrow0 + 32 + quad * 8);
    const bf16x8 b1lo = *(const bf16x8*)(qrow1 + quad * 8);
    const bf16x8 b1hi = *(const bf16x8*)(qrow1 + 32 + quad * 8);

    const int kend = (kc0 + 512 < Lb) ? kc0 + 512 : Lb;
    float lacc0 = 0.f, lacc1 = 0.f;

    for (int kt = kc0; kt < kend; kt += 64) {
        __syncthreads();
        #pragma unroll
        for (int i = 0; i < 2; ++i) {
            const int s = i * 256 + tid;
            const int row = s >> 3, cc = s & 7, c = cc ^ (row & 7);
            gld_lds16(karr + (size_t)(kt + row) * DKc + c * 8,
                      Ks + (i * 256 + wave * 64) * 8);
        }
        __syncthreads();

        #pragma unroll
        for (int t = 0; t < 4; ++t) {
            const int r = t * 16 + l16;
            const bf16x8 alo = *(const bf16x8*)(Ks + (r * 8 + (quad ^ (r & 7))) * 8);
            const bf16x8 ahi = *(const bf16x8*)(Ks + (r * 8 + ((4 + quad) ^ (r & 7))) * 8);
            f32x4 c0 = {0.f, 0.f, 0.f, 0.f}, c1 = {0.f, 0.f, 0.f, 0.f};
            c0 = __builtin_amdgcn_mfma_f32_16x16x32_bf16(alo, b0lo, c0, 0, 0, 0);
            c0 = __builtin_amdgcn_mfma_f32_16x16x32_bf16(ahi, b0hi, c0, 0, 0, 0);
            c1 = __builtin_amdgcn_mfma_f32_16x16x32_bf16(alo, b1lo, c1, 0, 0, 0);
            c1 = __builtin_amdgcn_mfma_f32_16x16x32_bf16(ahi, b1hi, c1, 0, 0, 0);
            #pragma unroll
            for (int rr = 0; rr < 4; ++rr) {
                const bool kv = (kt + t * 16 + quad * 4 + rr) < Lb;
                lacc0 += kv ? __expf(c0[rr]) : 0.f;
                lacc1 += kv ? __expf(c1[rr]) : 0.f;
            }
        }
    }
    lacc0 += __shfl_xor(lacc0, 16, 64); lacc0 += __shfl_xor(lacc0, 32, 64);
    lacc1 += __shfl_xor(lacc1, 16, 64); lacc1 += __shfl_xor(lacc1, 32, 64);
    float* __restrict__ rp = ws + RPOFF + ((size_t)blockIdx.z * 64 + bh) * Sc;
    if (quad == 0) rp[q0 + l16]      = lacc0;
    if (quad == 1) rp[q0 + 16 + l16] = lacc1;
}

// ---------------------------------------------------------------------------
// Kernel 2b: liarr[q] = 1 / sum over valid k-chunks of rp.
// ---------------------------------------------------------------------------
__global__ __launch_bounds__(256) void rowsum_reduce_kernel(
    const int* __restrict__ L, float* __restrict__ ws)
{
    const int bh = blockIdx.y;
    const int q  = blockIdx.x * 256 + threadIdx.x;
    const int nc = (L[bh >> 4] + 511) >> 9;
    float acc = 0.f;
    for (int c = 0; c < nc; ++c)
        acc += ws[RPOFF + ((size_t)c * 64 + bh) * Sc + q];
    ws[LIOFF + (size_t)bh * Sc + q] = 1.0f / acc;
}

// ---------------------------------------------------------------------------
// Kernel 3a: partial column sums over a 512-query chunk, LDS-staged Q stream.
// Block: (bh, k-tile of 128 = 4 waves x 32 k, q-chunk of 512).
// ---------------------------------------------------------------------------
__global__ __launch_bounds__(256) void colsum_part_kernel(
    const int* __restrict__ L, float* __restrict__ ws)
{
    const int bh = blockIdx.x;
    const int b  = bh >> 4;
    const int Lb = L[b];
    const int qc0 = blockIdx.z * 512;
    if (blockIdx.y * 128 >= Lb || qc0 >= Lb) return;   // block-uniform exit

    const int tid  = threadIdx.x;
    const int wave = tid >> 6;
    const int lane = tid & 63;
    const int k0 = blockIdx.y * 128 + wave * 32;
    const int l16 = lane & 15, quad = lane >> 4;

    const short* __restrict__ qarr = (const short*)(ws + QOFF) + (size_t)bh * Sc * DKc;
    const short* __restrict__ karr = (const short*)(ws + KOFF) + (size_t)bh * Sc * DKc;
    const float* __restrict__ liarr = ws + LIOFF + (size_t)bh * Sc;

    __shared__ __align__(16) short Qs[64 * 64];   // 8 KB, swizzled slots
    __shared__ __align__(16) float Lis[64];       // liarr tile

    // K fragments (fixed for the whole chunk), straight from global.
    const short* krow0 = karr + (size_t)(k0 + l16) * DKc;
    const short* krow1 = karr + (size_t)(k0 + 16 + l16) * DKc;
    const bf16x8 a0lo = *(const bf16x8*)(krow0 + quad * 8);
    const bf16x8 a0hi = *(const bf16x8*)(krow0 + 32 + quad * 8);
    const bf16x8 a1lo = *(const bf16x8*)(krow1 + quad * 8);
    const bf16x8 a1hi = *(const bf16x8*)(krow1 + 32 + quad * 8);

    const int qend = (qc0 + 512 < Lb) ? qc0 + 512 : Lb;
    float w0[4] = {0.f, 0.f, 0.f, 0.f};
    float w1[4] = {0.f, 0.f, 0.f, 0.f};

    for (int qt = qc0; qt < qend; qt += 64) {
        __syncthreads();
        #pragma unroll
        for (int i = 0; i < 2; ++i) {
            const int s = i * 256 + tid;
            const int row = s >> 3, cc = s & 7, c = cc ^ (row & 7);
            gld_lds16(qarr + (size_t)(qt + row) * DKc + c * 8,
                      Qs + (i * 256 + wave * 64) * 8);
        }
        if (tid < 16)
            gld_lds16(liarr + qt + tid * 4, Lis);
        __syncthreads();

        #pragma unroll
        for (int t = 0; t < 4; ++t) {
            const int r = t * 16 + l16;
            const bf16x8 blo = *(const bf16x8*)(Qs + (r * 8 + (quad ^ (r & 7))) * 8);
            const bf16x8 bhi = *(const bf16x8*)(Qs + (r * 8 + ((4 + quad) ^ (r & 7))) * 8);
            const float lv = (qt + r < Lb) ? Lis[r] : 0.f;
            f32x4 c0 = {0.f, 0.f, 0.f, 0.f}, c1 = {0.f, 0.f, 0.f, 0.f};
            c0 = __builtin_amdgcn_mfma_f32_16x16x32_bf16(a0lo, blo, c0, 0, 0, 0);
            c0 = __builtin_amdgcn_mfma_f32_16x16x32_bf16(a0hi, bhi, c0, 0, 0, 0);
            c1 = __builtin_amdgcn_mfma_f32_16x16x32_bf16(a1lo, blo, c1, 0, 0, 0);
            c1 = __builtin_amdgcn_mfma_f32_16x16x32_bf16(a1hi, bhi, c1, 0, 0, 0);
            #pragma unroll
            for (int rr = 0; rr < 4; ++rr) {
                w0[rr] += __expf(c0[rr]) * lv;
                w1[rr] += __expf(c1[rr]) * lv;
            }
        }
    }
    #pragma unroll
    for (int off = 1; off <= 8; off <<= 1) {
        #pragma unroll
        for (int rr = 0; rr < 4; ++rr) {
            w0[rr] += __shfl_xor(w0[rr], off, 64);
            w1[rr] += __shfl_xor(w1[rr], off, 64);
        }
    }
    if (l16 == 0) {
        float* __restrict__ cp = ws + CPOFF + ((size_t)blockIdx.z * 64 + bh) * Sc;
        #pragma unroll
        for (int rr = 0; rr < 4; ++rr) {
            cp[k0 + quad * 4 + rr]      = w0[rr];
            cp[k0 + 16 + quad * 4 + rr] = w1[rr];
        }
    }
}

// ---------------------------------------------------------------------------
// Kernel 3b: warr[k] = sum over valid q-chunks of cp.
// ---------------------------------------------------------------------------
__global__ __launch_bounds__(256) void colsum_reduce_kernel(
    const int* __restrict__ L, float* __restrict__ ws)
{
    const int bh = blockIdx.y;
    const int k  = blockIdx.x * 256 + threadIdx.x;
    const int nc = (L[bh >> 4] + 511) >> 9;
    float acc = 0.f;
    for (int c = 0; c < nc; ++c)
        acc += ws[CPOFF + ((size_t)c * 64 + bh) * Sc + k];
    ws[WOFF + (size_t)bh * Sc + k] = acc;
}

// ---------------------------------------------------------------------------
// Kernel 4a: partial y: yp[c][b,h,j] = sum_{s in chunk c} w[b,h,s]*x[b,s,j].
// ---------------------------------------------------------------------------
__global__ __launch_bounds__(256) void yw_part_kernel(
    const float* __restrict__ x, const int* __restrict__ L,
    float* __restrict__ ws)
{
    const int b  = blockIdx.y;
    const int j0 = blockIdx.x * 64;
    const int s0 = blockIdx.z * 128;
    const int Lb = L[b];
    if (s0 >= Lb) return;
    const int js = threadIdx.x & 63;
    const int sl = threadIdx.x >> 6;
    const float* __restrict__ warr = ws + WOFF + (size_t)b * NHc * Sc;
    const float* __restrict__ xb = x + (size_t)b * Sc * Hc;

    __shared__ float wt[128][20];
    __shared__ float red[4][16][64];

    #pragma unroll
    for (int i = 0; i < 8; ++i) {
        const int s = (threadIdx.x & 15) + 16 * i;
        const int h = threadIdx.x >> 4;
        float v = 0.f;
        if (s0 + s < Lb) v = warr[(size_t)h * Sc + s0 + s];
        wt[s][h] = v;
    }
    __syncthreads();

    float acc[16];
    #pragma unroll
    for (int h = 0; h < 16; ++h) acc[h] = 0.f;

    #pragma unroll 4
    for (int s = sl; s < 128; s += 4) {
        const float xv = xb[(size_t)(s0 + s) * Hc + j0 + js];
        const f32x4 wa = *(const f32x4*)&wt[s][0];
        const f32x4 wb = *(const f32x4*)&wt[s][4];
        const f32x4 wc = *(const f32x4*)&wt[s][8];
        const f32x4 wd = *(const f32x4*)&wt[s][12];
        #pragma unroll
        for (int h = 0; h < 4; ++h) acc[h]      += wa[h] * xv;
        #pragma unroll
        for (int h = 0; h < 4; ++h) acc[4 + h]  += wb[h] * xv;
        #pragma unroll
        for (int h = 0; h < 4; ++h) acc[8 + h]  += wc[h] * xv;
        #pragma unroll
        for (int h = 0; h < 4; ++h) acc[12 + h] += wd[h] * xv;
    }
    #pragma unroll
    for (int h = 0; h < 16; ++h) red[sl][h][js] = acc[h];
    __syncthreads();
    if (sl == 0) {
        float* __restrict__ yp = ws + YPOFF +
            ((size_t)blockIdx.z * Bc * NHc + (size_t)b * NHc) * Hc;
        #pragma unroll
        for (int h = 0; h < 16; ++h)
            yp[(size_t)h * Hc + j0 + js] =
                red[0][h][js] + red[1][h][js] + red[2][h][js] + red[3][h][js];
    }
}

// ---------------------------------------------------------------------------
// Kernel 4b: y[b,h,j] = sum over valid chunks of yp.
// ---------------------------------------------------------------------------
__global__ __launch_bounds__(256) void yw_reduce_kernel(
    const int* __restrict__ L, float* __restrict__ ws)
{
    const int b = blockIdx.y;
    const int i = blockIdx.x * 256 + threadIdx.x;   // over NHc*Hc = 16384
    const int nc = (L[b] + 127) >> 7;
    const float* __restrict__ p = ws + YPOFF + (size_t)b * NHc * Hc + i;
    float acc = 0.f;
    for (int c = 0; c < nc; ++c)
        acc += p[(size_t)c * Bc * NHc * Hc];
    ws[YOFF + (size_t)b * NHc * Hc + i] = acc;
}

// ---------------------------------------------------------------------------
// Kernel 5: csum[b,n] = sum_j y[b,h(n),j]*Wv[n,j] + bv[n]*L[b].
// ---------------------------------------------------------------------------
__global__ __launch_bounds__(256) void csum_kernel(
    const float* __restrict__ Wv, const float* __restrict__ bv,
    const int* __restrict__ L, float* __restrict__ ws)
{
    const int b = blockIdx.y;
    const int n = blockIdx.x * 256 + threadIdx.x;
    const int h0 = (blockIdx.x * 256) >> 6;
    __shared__ float ys[4][1024];
    const float* __restrict__ y = ws + YOFF + ((size_t)b * NHc + h0) * Hc;
    for (int i = threadIdx.x; i < 4096; i += 256) ys[i >> 10][i & 1023] = y[i];
    __syncthreads();
    const int hl = threadIdx.x >> 6;
    const float* __restrict__ wrow = Wv + (size_t)n * Hc;
    float acc = 0.f;
    for (int j = 0; j < Hc; j += 4) {
        float4 wv = *(const float4*)(wrow + j);
        acc += wv.x*ys[hl][j] + wv.y*ys[hl][j+1] + wv.z*ys[hl][j+2] + wv.w*ys[hl][j+3];
    }
    ws[CSOFF + (size_t)b * Hc + n] = acc + bv[n] * (float)L[b];
}

// ---------------------------------------------------------------------------
// Kernel 6: pooled[b,o] = (sum_n csum[b,n]*Wo[o,n]) / L[b] + bo[o].
// ---------------------------------------------------------------------------
__global__ __launch_bounds__(256) void out_kernel(
    const float* __restrict__ Wo, const float* __restrict__ bo,
    const int* __restrict__ L, const float* __restrict__ ws,
    float* __restrict__ out)
{
    const int b = blockIdx.y;
    const int n = blockIdx.x * 256 + threadIdx.x;
    __shared__ float cs[Hc];
    const float* __restrict__ c = ws + CSOFF + (size_t)b * Hc;
    for (int i = threadIdx.x; i < Hc; i += 256) cs[i] = c[i];
    __syncthreads();
    const float* __restrict__ wrow = Wo + (size_t)n * Hc;
    float acc = 0.f;
    for (int h = 0; h < Hc; h += 4) {
        float4 wv = *(const float4*)(wrow + h);
        acc += wv.x*cs[h] + wv.y*cs[h+1] + wv.z*cs[h+2] + wv.w*cs[h+3];
    }
    out[(size_t)b * Hc + n] = acc / (float)L[b] + bo[n];
}

// ---------------------------------------------------------------------------
extern "C" void kernel_launch(void* const* d_in, const int* in_sizes, int n_in,
                              void* d_out, int out_size, void* d_ws, size_t ws_size,
                              hipStream_t stream)
{
    (void)in_sizes; (void)n_in; (void)out_size; (void)ws_size;
    const float* x  = (const float*)d_in[0];
    const int*   L  = (const int*)d_in[1];
    const float* Wq = (const float*)d_in[2];
    const float* Wk = (const float*)d_in[3];
    const float* Wv = (const float*)d_in[4];
    const float* bv = (const float*)d_in[5];
    const float* Wo = (const float*)d_in[6];
    const float* bo = (const float*)d_in[7];
    float* out = (float*)d_out;
    float* ws  = (float*)d_ws;

    cvt_kernel<<<4096, 256, 0, stream>>>(x,  (short*)(ws + XHOFF), 1.0f);
    cvt_kernel<<<512,  256, 0, stream>>>(Wq, (short*)(ws + WQOFF), 0.125f);
    cvt_kernel<<<512,  256, 0, stream>>>(Wk, (short*)(ws + WKOFF), 1.0f);

    dim3 gp(Hc / 128, (Bc * Sc) / 128, 2);
    proj_mfma_kernel<<<gp, 256, 0, stream>>>(L, ws);

    dim3 gr(Bc * NHc, Sc / 128, 4);
    rowsum_part_kernel<<<gr, 256, 0, stream>>>(L, ws);
    dim3 grr(Sc / 256, Bc * NHc);
    rowsum_reduce_kernel<<<grr, 256, 0, stream>>>(L, ws);

    dim3 gcp(Bc * NHc, Sc / 128, 4);
    colsum_part_kernel<<<gcp, 256, 0, stream>>>(L, ws);
    colsum_reduce_kernel<<<grr, 256, 0, stream>>>(L, ws);

    dim3 gy(Hc / 64, Bc, Sc / 128);
    yw_part_kernel<<<gy, 256, 0, stream>>>(x, L, ws);

    dim3 gyr((NHc * Hc) / 256, Bc);
    yw_reduce_kernel<<<gyr, 256, 0, stream>>>(L, ws);

    dim3 gc(Hc / 256, Bc);
    csum_kernel<<<gc, 256, 0, stream>>>(Wv, bv, L, ws);

    dim3 go(Hc / 256, Bc);
    out_kernel<<<go, 256, 0, stream>>>(Wo, bo, L, ws, out);
}

// Round 7
// 241.397 us; speedup vs baseline: 11.4062x; 1.1456x over previous
//
#include <hip/hip_runtime.h>
#include <hip/hip_bf16.h>
#include <math.h>

// Problem constants (B,S,H fixed by setup_inputs)
constexpr int Bc = 4, Sc = 2048, Hc = 1024, NHc = 16, DKc = 64;

// Workspace layout (float units). Total ~61 MB.
constexpr size_t XHOFF = 0;                 // x bf16: 8,388,608 shorts
constexpr size_t QOFF  = 4194304;           // Q bf16 (bh,s,d)
constexpr size_t KOFF  = 8388608;           // K bf16 (bh,s,d)
constexpr size_t WQOFF = 12582912;          // Wq bf16 (pre-scaled 0.125)
constexpr size_t WKOFF = 13107200;          // Wk bf16
constexpr size_t LIOFF = 13631488;          // 1/rowsum per (bh,q)
constexpr size_t WOFF  = 13762560;          // attn column sums per (bh,k)
constexpr size_t YOFF  = 13893632;          // y[b,h,j] fp32 (4*16*1024)
constexpr size_t CSOFF = 13959168;          // csum[b,n] (4*1024)
constexpr size_t YPOFF = 13963264;          // y partials: 16 chunks x 65536
constexpr size_t RPOFF = 15011840;          // rowsum partials: 4*64*2048
constexpr size_t CPOFF = 15536128;          // colsum partials: 4*64*2048

typedef __attribute__((ext_vector_type(8))) short bf16x8;  // 8 bf16 (4 VGPRs)
typedef __attribute__((ext_vector_type(4))) float f32x4;

__device__ inline short f2bf(float v) {
    __hip_bfloat16 h = __float2bfloat16(v);
    return *reinterpret_cast<short*>(&h);
}

__device__ inline void gld_lds16(const void* g, void* l) {
    __builtin_amdgcn_global_load_lds(
        (const __attribute__((address_space(1))) unsigned int*)g,
        (__attribute__((address_space(3))) unsigned int*)l, 16, 0, 0);
}

// ---------------------------------------------------------------------------
// Kernel 0: fused fp32 -> bf16 conversion of x / Wq(x0.125) / Wk.
// Segment boundaries are multiples of one block's span (2048 elems).
// ---------------------------------------------------------------------------
__global__ __launch_bounds__(256) void cvt_all_kernel(
    const float* __restrict__ x, const float* __restrict__ Wq,
    const float* __restrict__ Wk, float* __restrict__ ws)
{
    const size_t i = ((size_t)blockIdx.x * 256 + threadIdx.x) * 8;
    const float* src; short* dst; float scale; size_t off;
    if (i < 8388608)       { src = x;  dst = (short*)(ws + XHOFF); off = i;            scale = 1.0f;   }
    else if (i < 9437184)  { src = Wq; dst = (short*)(ws + WQOFF); off = i - 8388608;  scale = 0.125f; }
    else                   { src = Wk; dst = (short*)(ws + WKOFF); off = i - 9437184;  scale = 1.0f;   }
    float4 a = *(const float4*)(src + off);
    float4 b = *(const float4*)(src + off + 4);
    bf16x8 o;
    o[0] = f2bf(a.x * scale); o[1] = f2bf(a.y * scale);
    o[2] = f2bf(a.z * scale); o[3] = f2bf(a.w * scale);
    o[4] = f2bf(b.x * scale); o[5] = f2bf(b.y * scale);
    o[6] = f2bf(b.z * scale); o[7] = f2bf(b.w * scale);
    *(bf16x8*)(dst + off) = o;
}

// ---------------------------------------------------------------------------
// Kernel 1: Q/K projections, bf16 MFMA, m97-style 128x128 tile.
// ---------------------------------------------------------------------------
__global__ __launch_bounds__(256) void proj_mfma_kernel(
    const int* __restrict__ L, float* __restrict__ ws)
{
    const int z  = blockIdx.z;
    const int m0 = blockIdx.y * 128;
    const int n0 = blockIdx.x * 128;
    const int b  = m0 >> 11;
    const int s0 = m0 & 2047;
    const int Lb = L[b];
    if (s0 >= Lb) return;

    const short* __restrict__ A = (const short*)(ws + XHOFF);
    const short* __restrict__ W = (const short*)(ws + (z == 0 ? WQOFF : WKOFF));
    short* __restrict__ Out = (short*)(ws + (z == 0 ? QOFF : KOFF));

    __shared__ __align__(16) short As[128 * 32];
    __shared__ __align__(16) short Bs[128 * 32];

    const int tid  = threadIdx.x;
    const int lane = tid & 63;
    const int wave = tid >> 6;
    const int l16  = lane & 15, quad = lane >> 4;
    const int wm = (wave & 1) * 64, wn = (wave >> 1) * 64;

    const int c0 = tid, c1 = tid + 256;
    const int r0 = c0 >> 2, g0 = (c0 & 3) * 8;
    const int r1 = c1 >> 2, g1 = (c1 & 3) * 8;
    short* lA0 = As + wave * 512;
    short* lA1 = As + 2048 + wave * 512;
    short* lB0 = Bs + wave * 512;
    short* lB1 = Bs + 2048 + wave * 512;

    const f32x4 z4 = {0.f, 0.f, 0.f, 0.f};
    f32x4 acc[4][4];
    #pragma unroll
    for (int i = 0; i < 4; ++i)
        #pragma unroll
        for (int j = 0; j < 4; ++j) acc[i][j] = z4;

    for (int k0 = 0; k0 < Hc; k0 += 32) {
        __syncthreads();
        gld_lds16(A + (size_t)(m0 + r0) * Hc + k0 + g0, lA0);
        gld_lds16(A + (size_t)(m0 + r1) * Hc + k0 + g1, lA1);
        gld_lds16(W + (size_t)(n0 + r0) * Hc + k0 + g0, lB0);
        gld_lds16(W + (size_t)(n0 + r1) * Hc + k0 + g1, lB1);
        __syncthreads();

        bf16x8 af[4], bfr[4];
        #pragma unroll
        for (int mt = 0; mt < 4; ++mt)
            af[mt] = *(const bf16x8*)(As + (wm + mt * 16 + l16) * 32 + quad * 8);
        #pragma unroll
        for (int nt = 0; nt < 4; ++nt)
            bfr[nt] = *(const bf16x8*)(Bs + (wn + nt * 16 + l16) * 32 + quad * 8);
        #pragma unroll
        for (int mt = 0; mt < 4; ++mt)
            #pragma unroll
            for (int nt = 0; nt < 4; ++nt)
                acc[mt][nt] = __builtin_amdgcn_mfma_f32_16x16x32_bf16(
                    af[mt], bfr[nt], acc[mt][nt], 0, 0, 0);
    }

    #pragma unroll
    for (int mt = 0; mt < 4; ++mt) {
        #pragma unroll
        for (int nt = 0; nt < 4; ++nt) {
            const int n = n0 + wn + nt * 16 + l16;
            const int h = n >> 6, d = n & 63;
            #pragma unroll
            for (int r = 0; r < 4; ++r) {
                const int s = s0 + wm + mt * 16 + quad * 4 + r;
                Out[(((size_t)b * NHc + h) * Sc + s) * DKc + d] =
                    f2bf(acc[mt][nt][r]);
            }
        }
    }
}

// ---------------------------------------------------------------------------
// Kernel 2a: partial row sums over a 512-key chunk; 128-row LDS K stages.
// XOR-swizzled chunk placement (slot = row*8 + (c ^ (row&7))).
// ---------------------------------------------------------------------------
__global__ __launch_bounds__(256) void rowsum_part_kernel(
    const int* __restrict__ L, float* __restrict__ ws)
{
    const int bh = blockIdx.x;
    const int b  = bh >> 4;
    const int Lb = L[b];
    const int kc0 = blockIdx.z * 512;
    if (blockIdx.y * 128 >= Lb || kc0 >= Lb) return;

    const int tid  = threadIdx.x;
    const int wave = tid >> 6;
    const int lane = tid & 63;
    const int q0 = blockIdx.y * 128 + wave * 32;
    const int l16 = lane & 15, quad = lane >> 4;

    const short* __restrict__ qarr = (const short*)(ws + QOFF) + (size_t)bh * Sc * DKc;
    const short* __restrict__ karr = (const short*)(ws + KOFF) + (size_t)bh * Sc * DKc;

    __shared__ __align__(16) short Ks[128 * 64];   // 16 KB, swizzled slots

    const short* qrow0 = qarr + (size_t)(q0 + l16) * DKc;
    const short* qrow1 = qarr + (size_t)(q0 + 16 + l16) * DKc;
    const bf16x8 b0lo = *(const bf16x8*)(qrow0 + quad * 8);
    const bf16x8 b0hi = *(const bf16x8*)(qrow0 + 32 + quad * 8);
    const bf16x8 b1lo = *(const bf16x8*)(qrow1 + quad * 8);
    const bf16x8 b1hi = *(const bf16x8*)(qrow1 + 32 + quad * 8);

    const int kend = (kc0 + 512 < Lb) ? kc0 + 512 : Lb;
    float lacc0 = 0.f, lacc1 = 0.f;

    for (int kt = kc0; kt < kend; kt += 128) {
        __syncthreads();
        #pragma unroll
        for (int i = 0; i < 4; ++i) {
            const int s = i * 256 + tid;
            const int row = s >> 3, cc = s & 7, c = cc ^ (row & 7);
            gld_lds16(karr + (size_t)(kt + row) * DKc + c * 8,
                      Ks + (i * 256 + wave * 64) * 8);
        }
        __syncthreads();

        #pragma unroll
        for (int t = 0; t < 8; ++t) {
            const int r = t * 16 + l16;
            const bf16x8 alo = *(const bf16x8*)(Ks + (r * 8 + (quad ^ (r & 7))) * 8);
            const bf16x8 ahi = *(const bf16x8*)(Ks + (r * 8 + ((4 + quad) ^ (r & 7))) * 8);
            f32x4 c0 = {0.f, 0.f, 0.f, 0.f}, c1 = {0.f, 0.f, 0.f, 0.f};
            c0 = __builtin_amdgcn_mfma_f32_16x16x32_bf16(alo, b0lo, c0, 0, 0, 0);
            c0 = __builtin_amdgcn_mfma_f32_16x16x32_bf16(ahi, b0hi, c0, 0, 0, 0);
            c1 = __builtin_amdgcn_mfma_f32_16x16x32_bf16(alo, b1lo, c1, 0, 0, 0);
            c1 = __builtin_amdgcn_mfma_f32_16x16x32_bf16(ahi, b1hi, c1, 0, 0, 0);
            #pragma unroll
            for (int rr = 0; rr < 4; ++rr) {
                const bool kv = (kt + t * 16 + quad * 4 + rr) < kend;
                lacc0 += kv ? __expf(c0[rr]) : 0.f;
                lacc1 += kv ? __expf(c1[rr]) : 0.f;
            }
        }
    }
    lacc0 += __shfl_xor(lacc0, 16, 64); lacc0 += __shfl_xor(lacc0, 32, 64);
    lacc1 += __shfl_xor(lacc1, 16, 64); lacc1 += __shfl_xor(lacc1, 32, 64);
    float* __restrict__ rp = ws + RPOFF + ((size_t)blockIdx.z * 64 + bh) * Sc;
    if (quad == 0) rp[q0 + l16]      = lacc0;
    if (quad == 1) rp[q0 + 16 + l16] = lacc1;
}

// ---------------------------------------------------------------------------
// Kernel 2b: liarr[q] = 1 / sum over valid k-chunks of rp.
// ---------------------------------------------------------------------------
__global__ __launch_bounds__(256) void rowsum_reduce_kernel(
    const int* __restrict__ L, float* __restrict__ ws)
{
    const int bh = blockIdx.y;
    const int q  = blockIdx.x * 256 + threadIdx.x;
    const int nc = (L[bh >> 4] + 511) >> 9;
    float acc = 0.f;
    for (int c = 0; c < nc; ++c)
        acc += ws[RPOFF + ((size_t)c * 64 + bh) * Sc + q];
    ws[LIOFF + (size_t)bh * Sc + q] = 1.0f / acc;
}

// ---------------------------------------------------------------------------
// Kernel 3a: partial column sums over a 512-query chunk; 128-row Q stages.
// ---------------------------------------------------------------------------
__global__ __launch_bounds__(256) void colsum_part_kernel(
    const int* __restrict__ L, float* __restrict__ ws)
{
    const int bh = blockIdx.x;
    const int b  = bh >> 4;
    const int Lb = L[b];
    const int qc0 = blockIdx.z * 512;
    if (blockIdx.y * 128 >= Lb || qc0 >= Lb) return;

    const int tid  = threadIdx.x;
    const int wave = tid >> 6;
    const int lane = tid & 63;
    const int k0 = blockIdx.y * 128 + wave * 32;
    const int l16 = lane & 15, quad = lane >> 4;

    const short* __restrict__ qarr = (const short*)(ws + QOFF) + (size_t)bh * Sc * DKc;
    const short* __restrict__ karr = (const short*)(ws + KOFF) + (size_t)bh * Sc * DKc;
    const float* __restrict__ liarr = ws + LIOFF + (size_t)bh * Sc;

    __shared__ __align__(16) short Qs[128 * 64];   // 16 KB, swizzled slots
    __shared__ __align__(16) float Lis[128];

    const short* krow0 = karr + (size_t)(k0 + l16) * DKc;
    const short* krow1 = karr + (size_t)(k0 + 16 + l16) * DKc;
    const bf16x8 a0lo = *(const bf16x8*)(krow0 + quad * 8);
    const bf16x8 a0hi = *(const bf16x8*)(krow0 + 32 + quad * 8);
    const bf16x8 a1lo = *(const bf16x8*)(krow1 + quad * 8);
    const bf16x8 a1hi = *(const bf16x8*)(krow1 + 32 + quad * 8);

    const int qend = (qc0 + 512 < Lb) ? qc0 + 512 : Lb;
    float w0[4] = {0.f, 0.f, 0.f, 0.f};
    float w1[4] = {0.f, 0.f, 0.f, 0.f};

    for (int qt = qc0; qt < qend; qt += 128) {
        __syncthreads();
        #pragma unroll
        for (int i = 0; i < 4; ++i) {
            const int s = i * 256 + tid;
            const int row = s >> 3, cc = s & 7, c = cc ^ (row & 7);
            gld_lds16(qarr + (size_t)(qt + row) * DKc + c * 8,
                      Qs + (i * 256 + wave * 64) * 8);
        }
        if (tid < 32)
            gld_lds16(liarr + qt + tid * 4, Lis);
        __syncthreads();

        #pragma unroll
        for (int t = 0; t < 8; ++t) {
            const int r = t * 16 + l16;
            const bf16x8 blo = *(const bf16x8*)(Qs + (r * 8 + (quad ^ (r & 7))) * 8);
            const bf16x8 bhi = *(const bf16x8*)(Qs + (r * 8 + ((4 + quad) ^ (r & 7))) * 8);
            const float lv = (qt + r < Lb) ? Lis[r] : 0.f;
            f32x4 c0 = {0.f, 0.f, 0.f, 0.f}, c1 = {0.f, 0.f, 0.f, 0.f};
            c0 = __builtin_amdgcn_mfma_f32_16x16x32_bf16(a0lo, blo, c0, 0, 0, 0);
            c0 = __builtin_amdgcn_mfma_f32_16x16x32_bf16(a0hi, bhi, c0, 0, 0, 0);
            c1 = __builtin_amdgcn_mfma_f32_16x16x32_bf16(a1lo, blo, c1, 0, 0, 0);
            c1 = __builtin_amdgcn_mfma_f32_16x16x32_bf16(a1hi, bhi, c1, 0, 0, 0);
            #pragma unroll
            for (int rr = 0; rr < 4; ++rr) {
                w0[rr] += __expf(c0[rr]) * lv;
                w1[rr] += __expf(c1[rr]) * lv;
            }
        }
    }
    #pragma unroll
    for (int off = 1; off <= 8; off <<= 1) {
        #pragma unroll
        for (int rr = 0; rr < 4; ++rr) {
            w0[rr] += __shfl_xor(w0[rr], off, 64);
            w1[rr] += __shfl_xor(w1[rr], off, 64);
        }
    }
    if (l16 == 0) {
        float* __restrict__ cp = ws + CPOFF + ((size_t)blockIdx.z * 64 + bh) * Sc;
        #pragma unroll
        for (int rr = 0; rr < 4; ++rr) {
            cp[k0 + quad * 4 + rr]      = w0[rr];
            cp[k0 + 16 + quad * 4 + rr] = w1[rr];
        }
    }
}

// ---------------------------------------------------------------------------
// Kernel 3b: warr[k] = sum over valid q-chunks of cp.
// ---------------------------------------------------------------------------
__global__ __launch_bounds__(256) void colsum_reduce_kernel(
    const int* __restrict__ L, float* __restrict__ ws)
{
    const int bh = blockIdx.y;
    const int k  = blockIdx.x * 256 + threadIdx.x;
    const int nc = (L[bh >> 4] + 511) >> 9;
    float acc = 0.f;
    for (int c = 0; c < nc; ++c)
        acc += ws[CPOFF + ((size_t)c * 64 + bh) * Sc + k];
    ws[WOFF + (size_t)bh * Sc + k] = acc;
}

// ---------------------------------------------------------------------------
// Kernel 4a: partial y: yp[c][b,h,j] = sum_{s in chunk c} w[b,h,s]*x[b,s,j].
// ---------------------------------------------------------------------------
__global__ __launch_bounds__(256) void yw_part_kernel(
    const float* __restrict__ x, const int* __restrict__ L,
    float* __restrict__ ws)
{
    const int b  = blockIdx.y;
    const int j0 = blockIdx.x * 64;
    const int s0 = blockIdx.z * 128;
    const int Lb = L[b];
    if (s0 >= Lb) return;
    const int js = threadIdx.x & 63;
    const int sl = threadIdx.x >> 6;
    const float* __restrict__ warr = ws + WOFF + (size_t)b * NHc * Sc;
    const float* __restrict__ xb = x + (size_t)b * Sc * Hc;

    __shared__ float wt[128][20];
    __shared__ float red[4][16][64];

    #pragma unroll
    for (int i = 0; i < 8; ++i) {
        const int s = (threadIdx.x & 15) + 16 * i;
        const int h = threadIdx.x >> 4;
        float v = 0.f;
        if (s0 + s < Lb) v = warr[(size_t)h * Sc + s0 + s];
        wt[s][h] = v;
    }
    __syncthreads();

    float acc[16];
    #pragma unroll
    for (int h = 0; h < 16; ++h) acc[h] = 0.f;

    #pragma unroll 4
    for (int s = sl; s < 128; s += 4) {
        const float xv = xb[(size_t)(s0 + s) * Hc + j0 + js];
        const f32x4 wa = *(const f32x4*)&wt[s][0];
        const f32x4 wb = *(const f32x4*)&wt[s][4];
        const f32x4 wc = *(const f32x4*)&wt[s][8];
        const f32x4 wd = *(const f32x4*)&wt[s][12];
        #pragma unroll
        for (int h = 0; h < 4; ++h) acc[h]      += wa[h] * xv;
        #pragma unroll
        for (int h = 0; h < 4; ++h) acc[4 + h]  += wb[h] * xv;
        #pragma unroll
        for (int h = 0; h < 4; ++h) acc[8 + h]  += wc[h] * xv;
        #pragma unroll
        for (int h = 0; h < 4; ++h) acc[12 + h] += wd[h] * xv;
    }
    #pragma unroll
    for (int h = 0; h < 16; ++h) red[sl][h][js] = acc[h];
    __syncthreads();
    if (sl == 0) {
        float* __restrict__ yp = ws + YPOFF +
            ((size_t)blockIdx.z * Bc * NHc + (size_t)b * NHc) * Hc;
        #pragma unroll
        for (int h = 0; h < 16; ++h)
            yp[(size_t)h * Hc + j0 + js] =
                red[0][h][js] + red[1][h][js] + red[2][h][js] + red[3][h][js];
    }
}

// ---------------------------------------------------------------------------
// Kernel 4b: y[b,h,j] = sum over valid chunks of yp.
// ---------------------------------------------------------------------------
__global__ __launch_bounds__(256) void yw_reduce_kernel(
    const int* __restrict__ L, float* __restrict__ ws)
{
    const int b = blockIdx.y;
    const int i = blockIdx.x * 256 + threadIdx.x;   // over NHc*Hc = 16384
    const int nc = (L[b] + 127) >> 7;
    const float* __restrict__ p = ws + YPOFF + (size_t)b * NHc * Hc + i;
    float acc = 0.f;
    for (int c = 0; c < nc; ++c)
        acc += p[(size_t)c * Bc * NHc * Hc];
    ws[YOFF + (size_t)b * NHc * Hc + i] = acc;
}

// ---------------------------------------------------------------------------
// Kernel 5: csum[b,n] = sum_j y[b,h(n),j]*Wv[n,j] + bv[n]*L[b].
// Wave-per-row coalesced GEMV: 64 lanes x float4 span a 1024-float row in
// 4 loads; 6-shuffle reduce per row; 16 rows per wave. Grid (16,4).
// ---------------------------------------------------------------------------
__global__ __launch_bounds__(256) void csum_kernel(
    const float* __restrict__ Wv, const float* __restrict__ bv,
    const int* __restrict__ L, float* __restrict__ ws)
{
    const int b = blockIdx.y;
    const int h = blockIdx.x;            // n0 = h*64, all in head h
    const int n0 = h * 64;
    const int lane = threadIdx.x & 63;
    const int wave = threadIdx.x >> 6;
    const float Lb = (float)L[b];

    __shared__ float ys[1024];
    const float* __restrict__ y = ws + YOFF + ((size_t)b * NHc + h) * Hc;
    for (int i = threadIdx.x; i < 1024; i += 256) ys[i] = y[i];
    __syncthreads();

    f32x4 yv[4];
    #pragma unroll
    for (int p = 0; p < 4; ++p) yv[p] = *(const f32x4*)&ys[p * 256 + lane * 4];

    #pragma unroll
    for (int r = 0; r < 16; ++r) {
        const int n = n0 + wave * 16 + r;
        const float* wrow = Wv + (size_t)n * Hc;
        float a = 0.f;
        #pragma unroll
        for (int p = 0; p < 4; ++p) {
            const f32x4 wv = *(const f32x4*)(wrow + p * 256 + lane * 4);
            a += wv[0]*yv[p][0] + wv[1]*yv[p][1] + wv[2]*yv[p][2] + wv[3]*yv[p][3];
        }
        #pragma unroll
        for (int off = 32; off > 0; off >>= 1) a += __shfl_xor(a, off, 64);
        if (lane == 0)
            ws[CSOFF + (size_t)b * Hc + n] = a + bv[n] * Lb;
    }
}

// ---------------------------------------------------------------------------
// Kernel 6: pooled[b,o] = (sum_n csum[b,n]*Wo[o,n]) / L[b] + bo[o].
// Same wave-per-row structure. Grid (16,4).
// ---------------------------------------------------------------------------
__global__ __launch_bounds__(256) void out_kernel(
    const float* __restrict__ Wo, const float* __restrict__ bo,
    const int* __restrict__ L, const float* __restrict__ ws,
    float* __restrict__ out)
{
    const int b = blockIdx.y;
    const int o0 = blockIdx.x * 64;
    const int lane = threadIdx.x & 63;
    const int wave = threadIdx.x >> 6;
    const float linv = 1.0f / (float)L[b];

    __shared__ float cs[1024];
    const float* __restrict__ c = ws + CSOFF + (size_t)b * Hc;
    for (int i = threadIdx.x; i < 1024; i += 256) cs[i] = c[i];
    __syncthreads();

    f32x4 cv[4];
    #pragma unroll
    for (int p = 0; p < 4; ++p) cv[p] = *(const f32x4*)&cs[p * 256 + lane * 4];

    #pragma unroll
    for (int r = 0; r < 16; ++r) {
        const int o = o0 + wave * 16 + r;
        const float* wrow = Wo + (size_t)o * Hc;
        float a = 0.f;
        #pragma unroll
        for (int p = 0; p < 4; ++p) {
            const f32x4 wv = *(const f32x4*)(wrow + p * 256 + lane * 4);
            a += wv[0]*cv[p][0] + wv[1]*cv[p][1] + wv[2]*cv[p][2] + wv[3]*cv[p][3];
        }
        #pragma unroll
        for (int off = 32; off > 0; off >>= 1) a += __shfl_xor(a, off, 64);
        if (lane == 0)
            out[(size_t)b * Hc + o] = a * linv + bo[o];
    }
}

// ---------------------------------------------------------------------------
extern "C" void kernel_launch(void* const* d_in, const int* in_sizes, int n_in,
                              void* d_out, int out_size, void* d_ws, size_t ws_size,
                              hipStream_t stream)
{
    (void)in_sizes; (void)n_in; (void)out_size; (void)ws_size;
    const float* x  = (const float*)d_in[0];
    const int*   L  = (const int*)d_in[1];
    const float* Wq = (const float*)d_in[2];
    const float* Wk = (const float*)d_in[3];
    const float* Wv = (const float*)d_in[4];
    const float* bv = (const float*)d_in[5];
    const float* Wo = (const float*)d_in[6];
    const float* bo = (const float*)d_in[7];
    float* out = (float*)d_out;
    float* ws  = (float*)d_ws;

    cvt_all_kernel<<<5120, 256, 0, stream>>>(x, Wq, Wk, ws);

    dim3 gp(Hc / 128, (Bc * Sc) / 128, 2);
    proj_mfma_kernel<<<gp, 256, 0, stream>>>(L, ws);

    dim3 gr(Bc * NHc, Sc / 128, 4);
    rowsum_part_kernel<<<gr, 256, 0, stream>>>(L, ws);
    dim3 grr(Sc / 256, Bc * NHc);
    rowsum_reduce_kernel<<<grr, 256, 0, stream>>>(L, ws);

    dim3 gcp(Bc * NHc, Sc / 128, 4);
    colsum_part_kernel<<<gcp, 256, 0, stream>>>(L, ws);
    colsum_reduce_kernel<<<grr, 256, 0, stream>>>(L, ws);

    dim3 gy(Hc / 64, Bc, Sc / 128);
    yw_part_kernel<<<gy, 256, 0, stream>>>(x, L, ws);

    dim3 gyr((NHc * Hc) / 256, Bc);
    yw_reduce_kernel<<<gyr, 256, 0, stream>>>(L, ws);

    dim3 gc(NHc, Bc);
    csum_kernel<<<gc, 256, 0, stream>>>(Wv, bv, L, ws);

    dim3 go(Hc / 64, Bc);
    out_kernel<<<go, 256, 0, stream>>>(Wo, bo, L, ws, out);
}